// Round 1
// baseline (8369.552 us; speedup 1.0000x reference)
//
#include <hip/hip_runtime.h>
#include <hip/hip_bf16.h>
#include <cstdint>
#include <cstddef>

#define VOCAB 32000
#define HIDDEN 1024
#define BATCH 32
#define SEQ 128

typedef __attribute__((ext_vector_type(8))) short short8v;
typedef __attribute__((ext_vector_type(4))) float float4v;

__device__ __forceinline__ float bf2f(unsigned short u) {
    unsigned int x = ((unsigned int)u) << 16;
    return __uint_as_float(x);
}
__device__ __forceinline__ unsigned short f2bf(float f) {
    unsigned int x = __float_as_uint(f);
    unsigned int r = x + 0x7fffu + ((x >> 16) & 1u);  // RNE
    return (unsigned short)(r >> 16);
}

// ---------------- pre-conversion kernels ----------------

// Convert W_hr, W_hz, W_hh (fp32 HxH) to bf16, packed [wr|wz|wh]
__global__ __launch_bounds__(256) void k_cvt_w(const float* __restrict__ wr,
                                               const float* __restrict__ wz,
                                               const float* __restrict__ wh,
                                               unsigned short* __restrict__ out) {
    const int n = HIDDEN * HIDDEN;
    for (int idx = blockIdx.x * 256 + threadIdx.x; idx < n; idx += gridDim.x * 256) {
        out[idx]         = f2bf(wr[idx]);
        out[n + idx]     = f2bf(wz[idx]);
        out[2 * n + idx] = f2bf(wh[idx]);
    }
}

// Transpose-convert W_ho (HIDDEN x VOCAB fp32) -> BT (VOCAB x HIDDEN bf16)
__global__ __launch_bounds__(256) void k_cvt_bt(const float* __restrict__ who,
                                                unsigned short* __restrict__ bt) {
    __shared__ float tile[64][65];
    const int nb = blockIdx.x;  // 500
    const int kb = blockIdx.y;  // 16
    const int t  = threadIdx.x;
    const int c  = t & 63;
    const int r0 = (t >> 6) * 16;
#pragma unroll
    for (int i = 0; i < 16; i++) {
        int r = r0 + i;  // k-row within tile
        tile[r][c] = who[(size_t)(kb * 64 + r) * VOCAB + nb * 64 + c];
    }
    __syncthreads();
#pragma unroll
    for (int i = 0; i < 16; i++) {
        int r = r0 + i;  // n-row within tile
        bt[(size_t)(nb * 64 + r) * HIDDEN + kb * 64 + c] = f2bf(tile[c][r]);
    }
}

__global__ __launch_bounds__(256) void k_init_h(const float* __restrict__ state,
                                                float* __restrict__ h) {
    int i = blockIdx.x * 256 + threadIdx.x;
    if (i < BATCH * HIDDEN) h[i] = state[i];
}

// ---------------- recurrence kernels (2 per step) ----------------

// Phase A: r and z gate pre-activations + sigmoid.
// grid = 256 blocks x 256 thr ; blk bits: [m(1)][b(5)][jb(2)]
__global__ __launch_bounds__(256) void k_rz(const int* __restrict__ x,
                                            const float* __restrict__ h,
                                            const unsigned short* __restrict__ wbf,  // [wr|wz] bf16
                                            const float* __restrict__ wxr,
                                            const float* __restrict__ wxz,
                                            const float* __restrict__ br,
                                            const float* __restrict__ bz,
                                            float* __restrict__ zbuf,
                                            unsigned short* __restrict__ rhbuf,
                                            int t) {
    const int blk = blockIdx.x;
    const int jb  = blk & 3;
    const int b   = (blk >> 2) & 31;
    const int m   = blk >> 7;  // 0 = r, 1 = z
    const int j   = jb * 256 + threadIdx.x;
    const int tok = x[b * SEQ + t];

    const unsigned short* W = wbf + (size_t)m * HIDDEN * HIDDEN;
    const float* hb = h + b * HIDDEN;

    float acc = 0.f;
#pragma unroll 8
    for (int k = 0; k < HIDDEN; k++) {
        acc += hb[k] * bf2f(W[k * HIDDEN + j]);
    }
    float xg   = (m ? wxz : wxr)[(size_t)tok * HIDDEN + j];
    float bias = (m ? bz : br)[j];
    float v = 1.f / (1.f + expf(-(acc + xg + bias)));
    if (m == 0) {
        rhbuf[b * HIDDEN + j] = f2bf(v * hb[j]);
    } else {
        zbuf[b * HIDDEN + j] = v;
    }
}

// Phase B: candidate matmul + state update + store h_t (bf16) for the big GEMM.
// grid = 128 blocks x 256 thr ; blk bits: [b(5)][jb(2)]
__global__ __launch_bounds__(256) void k_cand(const int* __restrict__ x,
                                              float* __restrict__ h,
                                              const unsigned short* __restrict__ whh,  // bf16
                                              const float* __restrict__ wxh,
                                              const float* __restrict__ bh,
                                              const float* __restrict__ zbuf,
                                              const unsigned short* __restrict__ rhbuf,
                                              unsigned short* __restrict__ hall,
                                              int t) {
    const int blk = blockIdx.x;
    const int jb  = blk & 3;
    const int b   = blk >> 2;
    const int j   = jb * 256 + threadIdx.x;
    const int tok = x[b * SEQ + t];

    const unsigned short* rh = rhbuf + b * HIDDEN;
    float acc = 0.f;
#pragma unroll 8
    for (int k = 0; k < HIDDEN; k++) {
        acc += bf2f(rh[k]) * bf2f(whh[k * HIDDEN + j]);
    }
    float a    = acc + wxh[(size_t)tok * HIDDEN + j] + bh[j];
    float cand = tanhf(a);
    float z    = zbuf[b * HIDDEN + j];
    float hv   = h[b * HIDDEN + j];
    float hn   = z * hv + (1.f - z) * cand;
    h[b * HIDDEN + j] = hn;
    hall[((size_t)t * BATCH + b) * HIDDEN + j] = f2bf(hn);
}

// ---------------- output-projection GEMM ----------------
// Out[4096][32000] = Hall[4096][1024](bf16) @ BT[32000][1024]^T (bf16) + b_o, fp32 out.
// 128x128 tile, BK=64, 4 waves (2x2), 4x4 16x16x32 fragments per wave.
#define BM 128
#define BN 128
#define BK 64

__global__ __launch_bounds__(256, 2) void k_gemm(const unsigned short* __restrict__ A,
                                                 const unsigned short* __restrict__ B,
                                                 const float* __restrict__ bo,
                                                 float* __restrict__ out) {
    __shared__ unsigned short As[BM * BK];
    __shared__ unsigned short Bs[BN * BK];
    const int nb   = blockIdx.x;  // 250
    const int mb   = blockIdx.y;  // 32
    const int tid  = threadIdx.x;
    const int lane = tid & 63;
    const int w    = tid >> 6;
    const int wm   = w >> 1, wn = w & 1;
    const int row0 = mb * BM, col0 = nb * BN;

    float4v acc[4][4];
#pragma unroll
    for (int i = 0; i < 4; i++)
#pragma unroll
        for (int j = 0; j < 4; j++) acc[i][j] = float4v{0.f, 0.f, 0.f, 0.f};

    for (int kt = 0; kt < HIDDEN / BK; kt++) {
        // stage 16KB A + 16KB B: 4x 16B chunks per thread each, reg-staged
#pragma unroll
        for (int i = 0; i < 4; i++) {
            int idx = i * 256 + tid;
            int row = idx >> 3;        // 8 x 16B per 128B row
            int off = (idx & 7) * 8;   // bf16 elems
            const unsigned short* ga = A + (size_t)(row0 + row) * HIDDEN + kt * BK + off;
            *(short8v*)&As[row * BK + off] = *(const short8v*)ga;
            const unsigned short* gb = B + (size_t)(col0 + row) * HIDDEN + kt * BK + off;
            *(short8v*)&Bs[row * BK + off] = *(const short8v*)gb;
        }
        __syncthreads();
#pragma unroll
        for (int kk = 0; kk < 2; kk++) {
            short8v af[4], bf[4];
#pragma unroll
            for (int i = 0; i < 4; i++) {
                int ar = wm * 64 + i * 16 + (lane & 15);
                af[i] = *(short8v*)&As[ar * BK + kk * 32 + (lane >> 4) * 8];
                int br = wn * 64 + i * 16 + (lane & 15);
                bf[i] = *(short8v*)&Bs[br * BK + kk * 32 + (lane >> 4) * 8];
            }
#pragma unroll
            for (int i = 0; i < 4; i++)
#pragma unroll
                for (int j = 0; j < 4; j++)
                    acc[i][j] = __builtin_amdgcn_mfma_f32_16x16x32_bf16(af[i], bf[j], acc[i][j], 0, 0, 0);
        }
        __syncthreads();
    }
    // epilogue: D row = 4*(lane>>4)+r, col = lane&15
#pragma unroll
    for (int i = 0; i < 4; i++) {
        int grow = row0 + wm * 64 + i * 16 + (lane >> 4) * 4;
#pragma unroll
        for (int j = 0; j < 4; j++) {
            int gcol = col0 + wn * 64 + j * 16 + (lane & 15);
            float bias = bo[gcol];
#pragma unroll
            for (int r = 0; r < 4; r++) {
                out[(size_t)(grow + r) * VOCAB + gcol] = acc[i][j][r] + bias;
            }
        }
    }
}

// ---------------- host ----------------

extern "C" void kernel_launch(void* const* d_in, const int* in_sizes, int n_in,
                              void* d_out, int out_size, void* d_ws, size_t ws_size,
                              hipStream_t stream) {
    const int*   x     = (const int*)d_in[0];
    const float* state = (const float*)d_in[1];
    const float* W_xr  = (const float*)d_in[2];
    const float* W_hr  = (const float*)d_in[3];
    const float* b_r   = (const float*)d_in[4];
    const float* W_xz  = (const float*)d_in[5];
    const float* W_hz  = (const float*)d_in[6];
    const float* b_z   = (const float*)d_in[7];
    const float* W_xh  = (const float*)d_in[8];
    const float* W_hh  = (const float*)d_in[9];
    const float* b_h   = (const float*)d_in[10];
    const float* W_ho  = (const float*)d_in[11];
    const float* b_o   = (const float*)d_in[12];

    float* out    = (float*)d_out;
    float* hstate = out + (size_t)SEQ * BATCH * VOCAB;  // final-state slot doubles as live h

    // ws layout (bytes):
    //   0        : hall  bf16 [SEQ*BATCH][HIDDEN]  (8 MB)
    //   8388608  : wbf   bf16 [wr|wz|wh]           (6 MB)
    //   14680064 : zbuf  fp32 [B][H]               (128 KB)
    //   14811136 : rhbuf bf16 [B][H]               (64 KB)
    //   14876672 : bt    bf16 [VOCAB][HIDDEN]      (62.5 MB)   total ~76.7 MB
    char* ws = (char*)d_ws;
    unsigned short* hall  = (unsigned short*)ws;
    unsigned short* wbf   = (unsigned short*)(ws + 8388608);
    float*          zbuf  = (float*)(ws + 14680064);
    unsigned short* rhbuf = (unsigned short*)(ws + 14811136);
    unsigned short* bt    = (unsigned short*)(ws + 14876672);

    k_cvt_w<<<512, 256, 0, stream>>>(W_hr, W_hz, W_hh, wbf);
    k_cvt_bt<<<dim3(500, 16), 256, 0, stream>>>(W_ho, bt);
    k_init_h<<<128, 256, 0, stream>>>(state, hstate);

    for (int t = 0; t < SEQ; t++) {
        k_rz<<<256, 256, 0, stream>>>(x, hstate, wbf, W_xr, W_xz, b_r, b_z, zbuf, rhbuf, t);
        k_cand<<<128, 256, 0, stream>>>(x, hstate, wbf + 2 * HIDDEN * HIDDEN, W_xh, b_h,
                                        zbuf, rhbuf, hall, t);
    }

    k_gemm<<<dim3(250, 32), 256, 0, stream>>>(hall, bt, b_o, out);
}

// Round 2
// 4496.781 us; speedup vs baseline: 1.8612x; 1.8612x over previous
//
#include <hip/hip_runtime.h>
#include <hip/hip_bf16.h>
#include <cstdint>
#include <cstddef>

#define VOCAB 32000
#define HIDDEN 1024
#define BATCH 32
#define SEQ 128

typedef __attribute__((ext_vector_type(8))) short short8v;
typedef __attribute__((ext_vector_type(4))) float float4v;

__device__ __forceinline__ float bf2f(unsigned short u) {
    unsigned int x = ((unsigned int)u) << 16;
    return __uint_as_float(x);
}
__device__ __forceinline__ unsigned short f2bf(float f) {
    unsigned int x = __float_as_uint(f);
    unsigned int r = x + 0x7fffu + ((x >> 16) & 1u);  // RNE
    return (unsigned short)(r >> 16);
}

// ---------------- pre-conversion: transpose fp32 [rows][cols] -> bf16 [cols][rows] ----------------
// grid: (cols/64, rows/64), block 256
__global__ __launch_bounds__(256) void k_transpose_bf(const float* __restrict__ in,
                                                      unsigned short* __restrict__ out,
                                                      int cols, int rows) {
    __shared__ float tile[64][65];
    const int jb = blockIdx.x;
    const int kb = blockIdx.y;
    const int t  = threadIdx.x;
    const int c  = t & 63;
    const int r0 = (t >> 6) * 16;
#pragma unroll
    for (int i = 0; i < 16; i++) {
        int r = r0 + i;
        tile[r][c] = in[(size_t)(kb * 64 + r) * cols + jb * 64 + c];
    }
    __syncthreads();
#pragma unroll
    for (int i = 0; i < 16; i++) {
        int r = r0 + i;
        out[(size_t)(jb * 64 + r) * rows + kb * 64 + c] = f2bf(tile[c][r]);
    }
}

__global__ __launch_bounds__(256) void k_init_hbf(const float* __restrict__ state,
                                                  unsigned short* __restrict__ hbf) {
    int i = blockIdx.x * 256 + threadIdx.x;
    if (i < BATCH * HIDDEN) hbf[i] = f2bf(state[i]);
}

// ---------------- persistent recurrence kernel ----------------
// 64 blocks x 64 threads (1 wave/block).
// group g = bid>>5 owns batches [g*16, g*16+16); jsl = bid&31 owns cols [jsl*32, jsl*32+32).
// Groups are fully independent; within a group, 2 flag-barriers per step.

__device__ __forceinline__ void group_barrier(unsigned int* c, unsigned int expected) {
    __threadfence();  // release: drain stores, write back L2 (cross-XCD visibility)
    if (threadIdx.x == 0) {
        __hip_atomic_fetch_add(c, 1u, __ATOMIC_RELAXED, __HIP_MEMORY_SCOPE_AGENT);
    }
    unsigned int v;
    do {
        v = __hip_atomic_load(c, __ATOMIC_RELAXED, __HIP_MEMORY_SCOPE_AGENT);
        if (v < expected) __builtin_amdgcn_s_sleep(1);
    } while (v < expected);
    __threadfence();  // acquire: invalidate stale cached lines
}

__global__ __launch_bounds__(64) void k_rnn(const int* __restrict__ x,
                                            const float* __restrict__ state,
                                            const unsigned short* __restrict__ wrt,
                                            const unsigned short* __restrict__ wzt,
                                            const unsigned short* __restrict__ wht,
                                            const float* __restrict__ W_xr, const float* __restrict__ b_r,
                                            const float* __restrict__ W_xz, const float* __restrict__ b_z,
                                            const float* __restrict__ W_xh, const float* __restrict__ b_h,
                                            unsigned short* __restrict__ hbf,   // [2][32][1024]
                                            unsigned short* __restrict__ rh,    // [32][1024]
                                            unsigned short* __restrict__ hall,  // [128][32][1024]
                                            float* __restrict__ hstate_out,     // [32][1024]
                                            unsigned int* cnt) {                // [2][256]
    const int bid = blockIdx.x;
    const int g   = bid >> 5;
    const int jsl = bid & 31;
    const int l   = threadIdx.x;
    const int lhi = l >> 4;   // 0..3
    const int llo = l & 15;   // 0..15

    const int j0 = jsl * 32;
    const int b0 = g * 16;
    unsigned int* mycnt = cnt + g * 256;

    // lane's 8 output elems: (b = b0 + 4*lhi + r, j = j0 + jt*16 + llo)
    float4v hO[2];
#pragma unroll
    for (int jt = 0; jt < 2; jt++)
#pragma unroll
        for (int r = 0; r < 4; r++)
            hO[jt][r] = state[(b0 + 4 * lhi + r) * HIDDEN + j0 + jt * 16 + llo];

    for (int t = 0; t < SEQ; t++) {
        const unsigned short* hcur = hbf + (t & 1) * (BATCH * HIDDEN);
        unsigned short* hnext      = hbf + ((t + 1) & 1) * (BATCH * HIDDEN);

        int tok[4];
#pragma unroll
        for (int r = 0; r < 4; r++) tok[r] = x[(b0 + 4 * lhi + r) * SEQ + t];

        // ---- Phase A: r gate ----
        float4v accR[2];
#pragma unroll
        for (int jt = 0; jt < 2; jt++) {
            int jc = j0 + jt * 16 + llo;
            float bv = b_r[jc];
#pragma unroll
            for (int r = 0; r < 4; r++)
                accR[jt][r] = W_xr[(size_t)tok[r] * HIDDEN + jc] + bv;
        }
#pragma unroll 4
        for (int ks = 0; ks < 32; ks++) {
            int k8 = ks * 32 + lhi * 8;
            short8v af = *(const short8v*)&hcur[(b0 + llo) * HIDDEN + k8];
#pragma unroll
            for (int jt = 0; jt < 2; jt++) {
                short8v bf = *(const short8v*)&wrt[(size_t)(j0 + jt * 16 + llo) * HIDDEN + k8];
                accR[jt] = __builtin_amdgcn_mfma_f32_16x16x32_bf16(af, bf, accR[jt], 0, 0, 0);
            }
        }
#pragma unroll
        for (int jt = 0; jt < 2; jt++)
#pragma unroll
            for (int r = 0; r < 4; r++) {
                float rv  = 1.f / (1.f + __expf(-accR[jt][r]));
                float rhv = rv * hO[jt][r];
                rh[(b0 + 4 * lhi + r) * HIDDEN + j0 + jt * 16 + llo] = f2bf(rhv);
            }
        group_barrier(&mycnt[2 * t], 32u);

        // ---- Phase B: z gate + candidate + update ----
        float4v accZ[2], accC[2];
#pragma unroll
        for (int jt = 0; jt < 2; jt++) {
            int jc = j0 + jt * 16 + llo;
            float bzv = b_z[jc];
            float bhv = b_h[jc];
#pragma unroll
            for (int r = 0; r < 4; r++) {
                accZ[jt][r] = W_xz[(size_t)tok[r] * HIDDEN + jc] + bzv;
                accC[jt][r] = W_xh[(size_t)tok[r] * HIDDEN + jc] + bhv;
            }
        }
#pragma unroll 4
        for (int ks = 0; ks < 32; ks++) {
            int k8 = ks * 32 + lhi * 8;
            short8v afh = *(const short8v*)&hcur[(b0 + llo) * HIDDEN + k8];
            short8v afr = *(const short8v*)&rh[(b0 + llo) * HIDDEN + k8];
#pragma unroll
            for (int jt = 0; jt < 2; jt++) {
                short8v bz8 = *(const short8v*)&wzt[(size_t)(j0 + jt * 16 + llo) * HIDDEN + k8];
                short8v bh8 = *(const short8v*)&wht[(size_t)(j0 + jt * 16 + llo) * HIDDEN + k8];
                accZ[jt] = __builtin_amdgcn_mfma_f32_16x16x32_bf16(afh, bz8, accZ[jt], 0, 0, 0);
                accC[jt] = __builtin_amdgcn_mfma_f32_16x16x32_bf16(afr, bh8, accC[jt], 0, 0, 0);
            }
        }
#pragma unroll
        for (int jt = 0; jt < 2; jt++)
#pragma unroll
            for (int r = 0; r < 4; r++) {
                int b  = b0 + 4 * lhi + r;
                int jc = j0 + jt * 16 + llo;
                float z = 1.f / (1.f + __expf(-accZ[jt][r]));
                float a = accC[jt][r];
                a = fminf(15.f, fmaxf(-15.f, a));
                float e2   = __expf(2.f * a);
                float cand = (e2 - 1.f) / (e2 + 1.f);
                float hn   = z * hO[jt][r] + (1.f - z) * cand;
                hO[jt][r]  = hn;
                unsigned short hb = f2bf(hn);
                hnext[b * HIDDEN + jc] = hb;
                hall[((size_t)t * BATCH + b) * HIDDEN + jc] = hb;
            }
        group_barrier(&mycnt[2 * t + 1], 32u);
    }

    // final state (fp32, kept exactly in registers)
#pragma unroll
    for (int jt = 0; jt < 2; jt++)
#pragma unroll
        for (int r = 0; r < 4; r++)
            hstate_out[(b0 + 4 * lhi + r) * HIDDEN + j0 + jt * 16 + llo] = hO[jt][r];
}

// ---------------- output-projection GEMM ----------------
// Out[4096][32000] = Hall[4096][1024](bf16) @ BT[32000][1024]^T (bf16) + b_o, fp32 out.
// 128x128 tile, BK=64, 4 waves (2x2), 4x4 16x16x32 fragments per wave.
// Staging via global_load_lds width=16 (dest linear in lane order: byte off = tid*16).
#define BM 128
#define BN 128
#define BK 64

__device__ __forceinline__ void gload_lds16(const void* g, void* l) {
    __builtin_amdgcn_global_load_lds((const __attribute__((address_space(1))) void*)g,
                                     (__attribute__((address_space(3))) void*)l, 16, 0, 0);
}

__global__ __launch_bounds__(256, 2) void k_gemm(const unsigned short* __restrict__ A,
                                                 const unsigned short* __restrict__ B,
                                                 const float* __restrict__ bo,
                                                 float* __restrict__ out) {
    __shared__ unsigned short As[BM * BK];
    __shared__ unsigned short Bs[BN * BK];
    const int nb   = blockIdx.x;  // 250
    const int mb   = blockIdx.y;  // 32
    const int tid  = threadIdx.x;
    const int lane = tid & 63;
    const int w    = tid >> 6;
    const int wm   = w >> 1, wn = w & 1;
    const int row0 = mb * BM, col0 = nb * BN;

    float4v acc[4][4];
#pragma unroll
    for (int i = 0; i < 4; i++)
#pragma unroll
        for (int j = 0; j < 4; j++) acc[i][j] = float4v{0.f, 0.f, 0.f, 0.f};

    for (int kt = 0; kt < HIDDEN / BK; kt++) {
        // stage 16KB A + 16KB B via async global->LDS, 4x16B per thread each
#pragma unroll
        for (int i = 0; i < 4; i++) {
            int s   = i * 256 + tid;
            int row = s >> 3;        // 8 x 16B per 128B row
            int off = (s & 7) * 8;   // bf16 elems
            gload_lds16(A + (size_t)(row0 + row) * HIDDEN + kt * BK + off, &As[s * 8]);
            gload_lds16(B + (size_t)(col0 + row) * HIDDEN + kt * BK + off, &Bs[s * 8]);
        }
        __syncthreads();
#pragma unroll
        for (int kk = 0; kk < 2; kk++) {
            short8v af[4], bf[4];
#pragma unroll
            for (int i = 0; i < 4; i++) {
                int ar = wm * 64 + i * 16 + (lane & 15);
                af[i] = *(short8v*)&As[ar * BK + kk * 32 + (lane >> 4) * 8];
                int br = wn * 64 + i * 16 + (lane & 15);
                bf[i] = *(short8v*)&Bs[br * BK + kk * 32 + (lane >> 4) * 8];
            }
#pragma unroll
            for (int i = 0; i < 4; i++)
#pragma unroll
                for (int j = 0; j < 4; j++)
                    acc[i][j] = __builtin_amdgcn_mfma_f32_16x16x32_bf16(af[i], bf[j], acc[i][j], 0, 0, 0);
        }
        __syncthreads();
    }
#pragma unroll
    for (int i = 0; i < 4; i++) {
        int grow = row0 + wm * 64 + i * 16 + (lane >> 4) * 4;
#pragma unroll
        for (int j = 0; j < 4; j++) {
            int gcol   = col0 + wn * 64 + j * 16 + (lane & 15);
            float bias = bo[gcol];
#pragma unroll
            for (int r = 0; r < 4; r++) {
                out[(size_t)(grow + r) * VOCAB + gcol] = acc[i][j][r] + bias;
            }
        }
    }
}

// ---------------- host ----------------

extern "C" void kernel_launch(void* const* d_in, const int* in_sizes, int n_in,
                              void* d_out, int out_size, void* d_ws, size_t ws_size,
                              hipStream_t stream) {
    const int*   x     = (const int*)d_in[0];
    const float* state = (const float*)d_in[1];
    const float* W_xr  = (const float*)d_in[2];
    const float* W_hr  = (const float*)d_in[3];
    const float* b_r   = (const float*)d_in[4];
    const float* W_xz  = (const float*)d_in[5];
    const float* W_hz  = (const float*)d_in[6];
    const float* b_z   = (const float*)d_in[7];
    const float* W_xh  = (const float*)d_in[8];
    const float* W_hh  = (const float*)d_in[9];
    const float* b_h   = (const float*)d_in[10];
    const float* W_ho  = (const float*)d_in[11];
    const float* b_o   = (const float*)d_in[12];

    float* out    = (float*)d_out;
    float* hstate = out + (size_t)SEQ * BATCH * VOCAB;

    // ws layout (bytes):
    //   0        : hall bf16 [128*32][1024]   8,388,608
    //   8388608  : bt   bf16 [32000][1024]   65,536,000
    //   73924608 : wrt  bf16 [1024][1024]     2,097,152
    //   76021760 : wzt  bf16                  2,097,152
    //   78118912 : wht  bf16                  2,097,152
    //   80216064 : hbf  bf16 [2][32][1024]      131,072
    //   80347136 : rh   bf16 [32][1024]          65,536
    //   80412672 : cnt  u32  [2][256]             2,048
    char* ws = (char*)d_ws;
    unsigned short* hall = (unsigned short*)ws;
    unsigned short* bt   = (unsigned short*)(ws + 8388608);
    unsigned short* wrt  = (unsigned short*)(ws + 73924608);
    unsigned short* wzt  = (unsigned short*)(ws + 76021760);
    unsigned short* wht  = (unsigned short*)(ws + 78118912);
    unsigned short* hbf  = (unsigned short*)(ws + 80216064);
    unsigned short* rh   = (unsigned short*)(ws + 80347136);
    unsigned int*   cnt  = (unsigned int*)(ws + 80412672);

    hipMemsetAsync(cnt, 0, 2048, stream);
    k_transpose_bf<<<dim3(16, 16), 256, 0, stream>>>(W_hr, wrt, HIDDEN, HIDDEN);
    k_transpose_bf<<<dim3(16, 16), 256, 0, stream>>>(W_hz, wzt, HIDDEN, HIDDEN);
    k_transpose_bf<<<dim3(16, 16), 256, 0, stream>>>(W_hh, wht, HIDDEN, HIDDEN);
    k_transpose_bf<<<dim3(500, 16), 256, 0, stream>>>(W_ho, bt, VOCAB, HIDDEN);
    k_init_hbf<<<128, 256, 0, stream>>>(state, hbf);

    k_rnn<<<64, 64, 0, stream>>>(x, state, wrt, wzt, wht, W_xr, b_r, W_xz, b_z, W_xh, b_h,
                                 hbf, rh, hall, hstate, cnt);

    k_gemm<<<dim3(250, 32), 256, 0, stream>>>(hall, bt, b_o, out);
}

// Round 3
// 2925.692 us; speedup vs baseline: 2.8607x; 1.5370x over previous
//
#include <hip/hip_runtime.h>
#include <hip/hip_bf16.h>
#include <cstdint>
#include <cstddef>

#define VOCAB 32000
#define HIDDEN 1024
#define BATCH 32
#define SEQ 128

typedef __attribute__((ext_vector_type(8))) short short8v;
typedef __attribute__((ext_vector_type(4))) float float4v;

__device__ __forceinline__ float bf2f(unsigned short u) {
    unsigned int x = ((unsigned int)u) << 16;
    return __uint_as_float(x);
}
__device__ __forceinline__ unsigned short f2bf(float f) {
    unsigned int x = __float_as_uint(f);
    unsigned int r = x + 0x7fffu + ((x >> 16) & 1u);  // RNE
    return (unsigned short)(r >> 16);
}

// ---------------- pre-conversion: transpose fp32 [rows][cols] -> bf16 [cols][rows] ----------------
__global__ __launch_bounds__(256) void k_transpose_bf(const float* __restrict__ in,
                                                      unsigned short* __restrict__ out,
                                                      int cols, int rows) {
    __shared__ float tile[64][65];
    const int jb = blockIdx.x;
    const int kb = blockIdx.y;
    const int t  = threadIdx.x;
    const int c  = t & 63;
    const int r0 = (t >> 6) * 16;
#pragma unroll
    for (int i = 0; i < 16; i++) {
        int r = r0 + i;
        tile[r][c] = in[(size_t)(kb * 64 + r) * cols + jb * 64 + c];
    }
    __syncthreads();
#pragma unroll
    for (int i = 0; i < 16; i++) {
        int r = r0 + i;
        out[(size_t)(jb * 64 + r) * rows + kb * 64 + c] = f2bf(tile[c][r]);
    }
}

__global__ __launch_bounds__(256) void k_init_hbf(const float* __restrict__ state,
                                                  unsigned short* __restrict__ hbf) {
    int i = blockIdx.x * 256 + threadIdx.x;
    if (i < BATCH * HIDDEN) hbf[i] = f2bf(state[i]);
}

// ---------------- persistent recurrence kernel ----------------
// 128 blocks x 256 threads (4 waves). Block (g = bid>>6, jsl = bid&63):
// group g owns batches [g*16,g*16+16); block owns j-cols [jsl*16, jsl*16+16).
// Weights live in REGISTERS (96 VGPR/thread of MFMA B-fragments, wave w owns
// k in [w*256, w*256+256)). Phase A: r+z matmuls; Phase B: candidate matmul.
// Cross-block exchange (rh, h) via flag-array barrier: monotone tags, one
// release fence (wbl2) by tid0, per-wave acquire fence (inv) on exit.

__device__ __forceinline__ void group_barrier(unsigned int* flags, int myslot, unsigned int tag) {
    __syncthreads();  // all waves' global stores issued + vmcnt drained (compiler emits waitcnt before s_barrier)
    if (threadIdx.x == 0) {
        __builtin_amdgcn_fence(__ATOMIC_RELEASE, "agent");  // wbl2: push this XCD's dirty L2
        __hip_atomic_store(&flags[myslot], tag, __ATOMIC_RELAXED, __HIP_MEMORY_SCOPE_AGENT);
    }
    if (threadIdx.x < 64) {
        while (true) {
            unsigned int v = __hip_atomic_load(&flags[threadIdx.x], __ATOMIC_RELAXED,
                                               __HIP_MEMORY_SCOPE_AGENT);
            if (__all((int)(v >= tag))) break;
            __builtin_amdgcn_s_sleep(2);
        }
    }
    __syncthreads();
    __builtin_amdgcn_fence(__ATOMIC_ACQUIRE, "agent");  // inv: drop stale L1/L2 lines before reading peers' data
}

__global__ __launch_bounds__(256, 1) void k_rnn(const int* __restrict__ x,
                                                const float* __restrict__ state,
                                                const unsigned short* __restrict__ wrt,
                                                const unsigned short* __restrict__ wzt,
                                                const unsigned short* __restrict__ wht,
                                                const float* __restrict__ W_xr, const float* __restrict__ b_r,
                                                const float* __restrict__ W_xz, const float* __restrict__ b_z,
                                                const float* __restrict__ W_xh, const float* __restrict__ b_h,
                                                unsigned short* __restrict__ hbf,   // [2][32][1024]
                                                unsigned short* __restrict__ rh,    // [32][1024]
                                                unsigned short* __restrict__ hall,  // [128][32][1024]
                                                float* __restrict__ hstate_out,     // [32][1024]
                                                unsigned int* __restrict__ flags) { // [2][64]
    const int bid = blockIdx.x;
    const int g   = bid >> 6;
    const int jsl = bid & 63;
    const int j0  = jsl * 16;
    const int b0  = g * 16;
    const int tid = threadIdx.x;
    const int w   = tid >> 6;
    const int l   = tid & 63;
    const int llo = l & 15;
    const int lhi = l >> 4;
    const int bloc = tid >> 4;   // scalar ownership: b = b0+bloc
    const int je   = tid & 15;   //                   j = j0+je
    const int bg = b0 + bloc;
    const int jg = j0 + je;

    unsigned int* myflag = flags + g * 64;

    __shared__ float red[3][4][16][17];  // [mat][wave][m][n(+pad)]

    // ---- preload weight B-fragments into registers: wave w covers ks in [w*8, w*8+8) ----
    short8v wr[8], wz[8], wh[8];
#pragma unroll
    for (int i = 0; i < 8; i++) {
        const size_t off = (size_t)(j0 + llo) * HIDDEN + (w * 8 + i) * 32 + lhi * 8;
        wr[i] = *(const short8v*)&wrt[off];
        wz[i] = *(const short8v*)&wzt[off];
        wh[i] = *(const short8v*)&wht[off];
    }

    float hO = state[bg * HIDDEN + jg];  // own fp32 h element

    for (int t = 0; t < SEQ; t++) {
        const unsigned short* hcur = hbf + (t & 1) * (BATCH * HIDDEN);
        unsigned short* hnext      = hbf + ((t + 1) & 1) * (BATCH * HIDDEN);

        // embedding gathers for this thread's (b, j), issued early
        const int tok = x[bg * SEQ + t];
        const float xr = W_xr[(size_t)tok * HIDDEN + jg];
        const float xz = W_xz[(size_t)tok * HIDDEN + jg];
        const float xh = W_xh[(size_t)tok * HIDDEN + jg];

        // ---- Phase A: r and z matmuls over this wave's k-slice ----
        short8v af[8];
#pragma unroll
        for (int i = 0; i < 8; i++)
            af[i] = *(const short8v*)&hcur[(b0 + llo) * HIDDEN + (w * 8 + i) * 32 + lhi * 8];

        float4v accR = {0.f, 0.f, 0.f, 0.f}, accZ = {0.f, 0.f, 0.f, 0.f};
#pragma unroll
        for (int i = 0; i < 8; i++) {
            accR = __builtin_amdgcn_mfma_f32_16x16x32_bf16(af[i], wr[i], accR, 0, 0, 0);
            accZ = __builtin_amdgcn_mfma_f32_16x16x32_bf16(af[i], wz[i], accZ, 0, 0, 0);
        }
#pragma unroll
        for (int q = 0; q < 4; q++) {
            red[0][w][4 * lhi + q][llo] = accR[q];
            red[1][w][4 * lhi + q][llo] = accZ[q];
        }
        __syncthreads();
        float sr = red[0][0][bloc][je] + red[0][1][bloc][je] + red[0][2][bloc][je] +
                   red[0][3][bloc][je] + xr + b_r[jg];
        float sz = red[1][0][bloc][je] + red[1][1][bloc][je] + red[1][2][bloc][je] +
                   red[1][3][bloc][je] + xz + b_z[jg];
        float rv = 1.f / (1.f + __expf(-sr));
        float zv = 1.f / (1.f + __expf(-sz));
        rh[bg * HIDDEN + jg] = f2bf(rv * hO);

        group_barrier(myflag, jsl, 2 * (unsigned)t + 1);

        // ---- Phase B: candidate matmul ----
        float4v accC = {0.f, 0.f, 0.f, 0.f};
#pragma unroll
        for (int i = 0; i < 8; i++) {
            short8v ar = *(const short8v*)&rh[(b0 + llo) * HIDDEN + (w * 8 + i) * 32 + lhi * 8];
            accC = __builtin_amdgcn_mfma_f32_16x16x32_bf16(ar, wh[i], accC, 0, 0, 0);
        }
#pragma unroll
        for (int q = 0; q < 4; q++) red[2][w][4 * lhi + q][llo] = accC[q];
        __syncthreads();
        float scnd = red[2][0][bloc][je] + red[2][1][bloc][je] + red[2][2][bloc][je] +
                     red[2][3][bloc][je] + xh + b_h[jg];
        scnd = fminf(15.f, fmaxf(-15.f, scnd));
        float e2   = __expf(2.f * scnd);
        float cand = (e2 - 1.f) / (e2 + 1.f);
        float hn   = zv * hO + (1.f - zv) * cand;
        hO = hn;
        unsigned short hb = f2bf(hn);
        hnext[bg * HIDDEN + jg] = hb;
        hall[((size_t)t * BATCH + bg) * HIDDEN + jg] = hb;

        group_barrier(myflag, jsl, 2 * (unsigned)t + 2);
    }

    hstate_out[bg * HIDDEN + jg] = hO;
}

// ---------------- output-projection GEMM ----------------
// Out[4096][32000] = Hall[4096][1024](bf16) @ BT[32000][1024]^T (bf16) + b_o, fp32 out.
// 128x128 tile, BK=64, 4 waves (2x2), global_load_lds width=16 staging, XCD swizzle.
#define BM 128
#define BN 128
#define BK 64

__device__ __forceinline__ void gload_lds16(const void* g, void* l) {
    __builtin_amdgcn_global_load_lds((const __attribute__((address_space(1))) void*)g,
                                     (__attribute__((address_space(3))) void*)l, 16, 0, 0);
}

__global__ __launch_bounds__(256, 2) void k_gemm(const unsigned short* __restrict__ A,
                                                 const unsigned short* __restrict__ B,
                                                 const float* __restrict__ bo,
                                                 float* __restrict__ out) {
    __shared__ unsigned short As[BM * BK];
    __shared__ unsigned short Bs[BN * BK];
    // XCD-aware bijective swizzle of the flattened 8000-block grid (8000 % 8 == 0)
    const int wg   = blockIdx.y * 250 + blockIdx.x;
    const int swz  = (wg & 7) * 1000 + (wg >> 3);
    const int nb   = swz % 250;
    const int mb   = swz / 250;
    const int tid  = threadIdx.x;
    const int lane = tid & 63;
    const int w    = tid >> 6;
    const int wm   = w >> 1, wn = w & 1;
    const int row0 = mb * BM, col0 = nb * BN;

    float4v acc[4][4];
#pragma unroll
    for (int i = 0; i < 4; i++)
#pragma unroll
        for (int j = 0; j < 4; j++) acc[i][j] = float4v{0.f, 0.f, 0.f, 0.f};

    for (int kt = 0; kt < HIDDEN / BK; kt++) {
#pragma unroll
        for (int i = 0; i < 4; i++) {
            int s   = i * 256 + tid;
            int row = s >> 3;
            int off = (s & 7) * 8;
            gload_lds16(A + (size_t)(row0 + row) * HIDDEN + kt * BK + off, &As[s * 8]);
            gload_lds16(B + (size_t)(col0 + row) * HIDDEN + kt * BK + off, &Bs[s * 8]);
        }
        __syncthreads();
#pragma unroll
        for (int kk = 0; kk < 2; kk++) {
            short8v af[4], bf[4];
#pragma unroll
            for (int i = 0; i < 4; i++) {
                int ar = wm * 64 + i * 16 + (lane & 15);
                af[i] = *(short8v*)&As[ar * BK + kk * 32 + (lane >> 4) * 8];
                int br = wn * 64 + i * 16 + (lane & 15);
                bf[i] = *(short8v*)&Bs[br * BK + kk * 32 + (lane >> 4) * 8];
            }
#pragma unroll
            for (int i = 0; i < 4; i++)
#pragma unroll
                for (int j = 0; j < 4; j++)
                    acc[i][j] = __builtin_amdgcn_mfma_f32_16x16x32_bf16(af[i], bf[j], acc[i][j], 0, 0, 0);
        }
        __syncthreads();
    }
#pragma unroll
    for (int i = 0; i < 4; i++) {
        int grow = row0 + wm * 64 + i * 16 + (lane >> 4) * 4;
#pragma unroll
        for (int j = 0; j < 4; j++) {
            int gcol   = col0 + wn * 64 + j * 16 + (lane & 15);
            float bias = bo[gcol];
#pragma unroll
            for (int r = 0; r < 4; r++) {
                out[(size_t)(grow + r) * VOCAB + gcol] = acc[i][j][r] + bias;
            }
        }
    }
}

// ---------------- host ----------------

extern "C" void kernel_launch(void* const* d_in, const int* in_sizes, int n_in,
                              void* d_out, int out_size, void* d_ws, size_t ws_size,
                              hipStream_t stream) {
    const int*   x     = (const int*)d_in[0];
    const float* state = (const float*)d_in[1];
    const float* W_xr  = (const float*)d_in[2];
    const float* W_hr  = (const float*)d_in[3];
    const float* b_r   = (const float*)d_in[4];
    const float* W_xz  = (const float*)d_in[5];
    const float* W_hz  = (const float*)d_in[6];
    const float* b_z   = (const float*)d_in[7];
    const float* W_xh  = (const float*)d_in[8];
    const float* W_hh  = (const float*)d_in[9];
    const float* b_h   = (const float*)d_in[10];
    const float* W_ho  = (const float*)d_in[11];
    const float* b_o   = (const float*)d_in[12];

    float* out    = (float*)d_out;
    float* hstate = out + (size_t)SEQ * BATCH * VOCAB;

    // ws layout (bytes):
    //   0        : hall  bf16 [128*32][1024]   8,388,608
    //   8388608  : bt    bf16 [32000][1024]   65,536,000
    //   73924608 : wrt   bf16 [1024][1024]     2,097,152
    //   76021760 : wzt   bf16                  2,097,152
    //   78118912 : wht   bf16                  2,097,152
    //   80216064 : hbf   bf16 [2][32][1024]      131,072
    //   80347136 : rh    bf16 [32][1024]          65,536
    //   80412672 : flags u32  [2][64]               512
    char* ws = (char*)d_ws;
    unsigned short* hall  = (unsigned short*)ws;
    unsigned short* bt    = (unsigned short*)(ws + 8388608);
    unsigned short* wrt   = (unsigned short*)(ws + 73924608);
    unsigned short* wzt   = (unsigned short*)(ws + 76021760);
    unsigned short* wht   = (unsigned short*)(ws + 78118912);
    unsigned short* hbf   = (unsigned short*)(ws + 80216064);
    unsigned short* rh    = (unsigned short*)(ws + 80347136);
    unsigned int*   flags = (unsigned int*)(ws + 80412672);

    hipMemsetAsync(flags, 0, 512, stream);
    k_transpose_bf<<<dim3(16, 16), 256, 0, stream>>>(W_hr, wrt, HIDDEN, HIDDEN);
    k_transpose_bf<<<dim3(16, 16), 256, 0, stream>>>(W_hz, wzt, HIDDEN, HIDDEN);
    k_transpose_bf<<<dim3(16, 16), 256, 0, stream>>>(W_hh, wht, HIDDEN, HIDDEN);
    k_transpose_bf<<<dim3(500, 16), 256, 0, stream>>>(W_ho, bt, VOCAB, HIDDEN);
    k_init_hbf<<<128, 256, 0, stream>>>(state, hbf);

    k_rnn<<<128, 256, 0, stream>>>(x, state, wrt, wzt, wht, W_xr, b_r, W_xz, b_z, W_xh, b_h,
                                   hbf, rh, hall, hstate, flags);

    k_gemm<<<dim3(250, 32), 256, 0, stream>>>(hall, bt, b_o, out);
}

// Round 4
// 1722.991 us; speedup vs baseline: 4.8576x; 1.6980x over previous
//
#include <hip/hip_runtime.h>
#include <hip/hip_bf16.h>
#include <cstdint>
#include <cstddef>

#define VOCAB 32000
#define HIDDEN 1024
#define BATCH 32
#define SEQ 128

typedef __attribute__((ext_vector_type(8))) short short8v;
typedef __attribute__((ext_vector_type(4))) float float4v;

__device__ __forceinline__ float bf2f(unsigned short u) {
    unsigned int x = ((unsigned int)u) << 16;
    return __uint_as_float(x);
}
__device__ __forceinline__ unsigned short f2bf(float f) {
    unsigned int x = __float_as_uint(f);
    unsigned int r = x + 0x7fffu + ((x >> 16) & 1u);  // RNE
    return (unsigned short)(r >> 16);
}

// ---------------- pre-conversion: transpose fp32 [rows][cols] -> bf16 [cols][rows] ----------------
__global__ __launch_bounds__(256) void k_transpose_bf(const float* __restrict__ in,
                                                      unsigned short* __restrict__ out,
                                                      int cols, int rows) {
    __shared__ float tile[64][65];
    const int jb = blockIdx.x;
    const int kb = blockIdx.y;
    const int t  = threadIdx.x;
    const int c  = t & 63;
    const int r0 = (t >> 6) * 16;
#pragma unroll
    for (int i = 0; i < 16; i++) {
        int r = r0 + i;
        tile[r][c] = in[(size_t)(kb * 64 + r) * cols + jb * 64 + c];
    }
    __syncthreads();
#pragma unroll
    for (int i = 0; i < 16; i++) {
        int r = r0 + i;
        out[(size_t)(jb * 64 + r) * rows + kb * 64 + c] = f2bf(tile[c][r]);
    }
}

__global__ __launch_bounds__(256) void k_init_hbf(const float* __restrict__ state,
                                                  unsigned short* __restrict__ hbf) {
    int i = blockIdx.x * 256 + threadIdx.x;
    if (i < BATCH * HIDDEN) hbf[i] = f2bf(state[i]);
}

// ---------------- persistent recurrence kernel ----------------
// 128 blocks x 256 threads (4 waves). group g = bid>>6 owns batches [g*16,+16);
// block owns j-cols [jsl*16,+16). Weights live in LDS (96 KB of pre-formed MFMA
// B-fragments). Cross-block data goes through write-through (sc0 sc1) stores and
// cache-bypassing (sc0 sc1) loads -> NO agent fences anywhere (L2 stays warm for
// the read-only embedding tables). Flag barrier: explicit vmcnt(0) drain, tid0
// publishes relaxed agent-scope tag, wave 0 polls 64 flags with one 64-lane load.

// issue 8 x 16B coherent loads (stride 64B), NO wait — pair with WAIT_VM0
#define LD8_SC(P, F0, F1, F2, F3, F4, F5, F6, F7)                      \
    asm volatile("global_load_dwordx4 %0, %8, off sc0 sc1\n\t"         \
                 "global_load_dwordx4 %1, %8, off offset:64 sc0 sc1\n\t"  \
                 "global_load_dwordx4 %2, %8, off offset:128 sc0 sc1\n\t" \
                 "global_load_dwordx4 %3, %8, off offset:192 sc0 sc1\n\t" \
                 "global_load_dwordx4 %4, %8, off offset:256 sc0 sc1\n\t" \
                 "global_load_dwordx4 %5, %8, off offset:320 sc0 sc1\n\t" \
                 "global_load_dwordx4 %6, %8, off offset:384 sc0 sc1\n\t" \
                 "global_load_dwordx4 %7, %8, off offset:448 sc0 sc1"     \
                 : "=&v"(F0), "=&v"(F1), "=&v"(F2), "=&v"(F3),         \
                   "=&v"(F4), "=&v"(F5), "=&v"(F6), "=&v"(F7)          \
                 : "v"(P)                                              \
                 : "memory")

#define WAIT_VM0 asm volatile("s_waitcnt vmcnt(0)" ::: "memory")

__device__ __forceinline__ void st_bf16_wt(unsigned short* p, unsigned short v) {
    unsigned int vv = v;
    asm volatile("global_store_short %0, %1, off sc0 sc1" ::"v"(p), "v"(vv) : "memory");
}

__device__ __forceinline__ void group_barrier(unsigned int* flags, int myslot, unsigned int tag) {
    WAIT_VM0;         // own write-through stores committed to coherent point
    __syncthreads();  // all waves of this block drained
    if (threadIdx.x == 0) {
        __hip_atomic_store(&flags[myslot], tag, __ATOMIC_RELAXED, __HIP_MEMORY_SCOPE_AGENT);
    }
    if (threadIdx.x < 64) {
        while (true) {
            unsigned int v = __hip_atomic_load(&flags[threadIdx.x], __ATOMIC_RELAXED,
                                               __HIP_MEMORY_SCOPE_AGENT);
            if (__all((int)(v >= tag))) break;
            __builtin_amdgcn_s_sleep(1);
        }
    }
    __syncthreads();
}

__global__ __launch_bounds__(256, 1) void k_rnn(const int* __restrict__ x,
                                                const float* __restrict__ state,
                                                const unsigned short* __restrict__ wrt,
                                                const unsigned short* __restrict__ wzt,
                                                const unsigned short* __restrict__ wht,
                                                const float* __restrict__ W_xr, const float* __restrict__ b_r,
                                                const float* __restrict__ W_xz, const float* __restrict__ b_z,
                                                const float* __restrict__ W_xh, const float* __restrict__ b_h,
                                                unsigned short* __restrict__ hbf,   // [2][32][1024]
                                                unsigned short* __restrict__ rhbuf, // [32][1024]
                                                unsigned short* __restrict__ hall,  // [128][32][1024]
                                                float* __restrict__ hstate_out,     // [32][1024]
                                                unsigned int* __restrict__ flags) { // [2][64]
    const int bid  = blockIdx.x;
    const int g    = bid >> 6;
    const int jsl  = bid & 63;
    const int j0   = jsl * 16;
    const int b0   = g * 16;
    const int tid  = threadIdx.x;
    const int w    = tid >> 6;
    const int l    = tid & 63;
    const int llo  = l & 15;
    const int lhi  = l >> 4;
    const int bloc = tid >> 4;
    const int je   = tid & 15;
    const int bg   = b0 + bloc;
    const int jg   = j0 + je;

    unsigned int* myflag = flags + g * 64;

    __shared__ short8v wlds[3][4][8][64];  // 96 KB: [mat][wave][ks-sub][lane]
    __shared__ float red[3][4][16][17];    // 13 KB: [mat][wave][m][n(+pad)]

    // ---- one-time: preload this block's weight B-fragments into LDS ----
    {
        const size_t base = (size_t)(j0 + llo) * HIDDEN + lhi * 8;
#pragma unroll
        for (int i = 0; i < 8; i++) {
            const size_t off = base + (size_t)(w * 8 + i) * 32;
            wlds[0][w][i][l] = *(const short8v*)&wrt[off];
            wlds[1][w][i][l] = *(const short8v*)&wzt[off];
            wlds[2][w][i][l] = *(const short8v*)&wht[off];
        }
    }
    const float brv = b_r[jg], bzv = b_z[jg], bhv = b_h[jg];
    float hO = state[bg * HIDDEN + jg];
    __syncthreads();

    for (int t = 0; t < SEQ; t++) {
        const unsigned short* hcur = hbf + (t & 1) * (BATCH * HIDDEN);
        unsigned short* hnext      = hbf + ((t + 1) & 1) * (BATCH * HIDDEN);

        // embedding gathers (plain cached loads — L2 stays warm, no inv fences)
        const int tok  = x[bg * SEQ + t];
        const float xr = W_xr[(size_t)tok * HIDDEN + jg];
        const float xz = W_xz[(size_t)tok * HIDDEN + jg];
        const float xh = W_xh[(size_t)tok * HIDDEN + jg];

        // ---- Phase A: r and z matmuls over this wave's k-slice ----
        short8v a0, a1, a2, a3, a4, a5, a6, a7;
        const unsigned short* pa = &hcur[(b0 + llo) * HIDDEN + w * 256 + lhi * 8];
        LD8_SC(pa, a0, a1, a2, a3, a4, a5, a6, a7);

        short8v fr[8], fz[8];
#pragma unroll
        for (int i = 0; i < 8; i++) {
            fr[i] = wlds[0][w][i][l];
            fz[i] = wlds[1][w][i][l];
        }
        WAIT_VM0;
        __builtin_amdgcn_sched_barrier(0);

        short8v af[8] = {a0, a1, a2, a3, a4, a5, a6, a7};
        float4v accR = {0.f, 0.f, 0.f, 0.f}, accZ = {0.f, 0.f, 0.f, 0.f};
#pragma unroll
        for (int i = 0; i < 8; i++) {
            accR = __builtin_amdgcn_mfma_f32_16x16x32_bf16(af[i], fr[i], accR, 0, 0, 0);
            accZ = __builtin_amdgcn_mfma_f32_16x16x32_bf16(af[i], fz[i], accZ, 0, 0, 0);
        }
#pragma unroll
        for (int q = 0; q < 4; q++) {
            red[0][w][4 * lhi + q][llo] = accR[q];
            red[1][w][4 * lhi + q][llo] = accZ[q];
        }
        __syncthreads();
        float sr = red[0][0][bloc][je] + red[0][1][bloc][je] + red[0][2][bloc][je] +
                   red[0][3][bloc][je] + xr + brv;
        float sz = red[1][0][bloc][je] + red[1][1][bloc][je] + red[1][2][bloc][je] +
                   red[1][3][bloc][je] + xz + bzv;
        float rv = 1.f / (1.f + __expf(-sr));
        float zv = 1.f / (1.f + __expf(-sz));
        st_bf16_wt(&rhbuf[bg * HIDDEN + jg], f2bf(rv * hO));

        group_barrier(myflag, jsl, 2 * (unsigned)t + 1);

        // ---- Phase B: candidate matmul ----
        short8v c0, c1, c2, c3, c4, c5, c6, c7;
        const unsigned short* pb = &rhbuf[(b0 + llo) * HIDDEN + w * 256 + lhi * 8];
        LD8_SC(pb, c0, c1, c2, c3, c4, c5, c6, c7);

        short8v fh[8];
#pragma unroll
        for (int i = 0; i < 8; i++) fh[i] = wlds[2][w][i][l];
        WAIT_VM0;
        __builtin_amdgcn_sched_barrier(0);

        short8v ar[8] = {c0, c1, c2, c3, c4, c5, c6, c7};
        float4v accC = {0.f, 0.f, 0.f, 0.f};
#pragma unroll
        for (int i = 0; i < 8; i++)
            accC = __builtin_amdgcn_mfma_f32_16x16x32_bf16(ar[i], fh[i], accC, 0, 0, 0);
#pragma unroll
        for (int q = 0; q < 4; q++) red[2][w][4 * lhi + q][llo] = accC[q];
        __syncthreads();
        float scnd = red[2][0][bloc][je] + red[2][1][bloc][je] + red[2][2][bloc][je] +
                     red[2][3][bloc][je] + xh + bhv;
        scnd = fminf(15.f, fmaxf(-15.f, scnd));
        float e2   = __expf(2.f * scnd);
        float cand = (e2 - 1.f) / (e2 + 1.f);
        float hn   = zv * hO + (1.f - zv) * cand;
        hO = hn;
        unsigned short hb = f2bf(hn);
        st_bf16_wt(&hnext[bg * HIDDEN + jg], hb);
        hall[((size_t)t * BATCH + bg) * HIDDEN + jg] = hb;  // plain: read only after kernel end

        group_barrier(myflag, jsl, 2 * (unsigned)t + 2);
    }

    hstate_out[bg * HIDDEN + jg] = hO;
}

// ---------------- output-projection GEMM ----------------
// Out[4096][32000] = Hall[4096][1024](bf16) @ BT[32000][1024]^T (bf16) + b_o, fp32 out.
// 128x128 tile, BK=64, 4 waves (2x2), global_load_lds width=16 staging, XCD swizzle.
#define BM 128
#define BN 128
#define BK 64

__device__ __forceinline__ void gload_lds16(const void* g, void* l) {
    __builtin_amdgcn_global_load_lds((const __attribute__((address_space(1))) void*)g,
                                     (__attribute__((address_space(3))) void*)l, 16, 0, 0);
}

__global__ __launch_bounds__(256, 2) void k_gemm(const unsigned short* __restrict__ A,
                                                 const unsigned short* __restrict__ B,
                                                 const float* __restrict__ bo,
                                                 float* __restrict__ out) {
    __shared__ unsigned short As[BM * BK];
    __shared__ unsigned short Bs[BN * BK];
    // XCD-aware bijective swizzle of the flattened 8000-block grid (8000 % 8 == 0)
    const int wg   = blockIdx.y * 250 + blockIdx.x;
    const int swz  = (wg & 7) * 1000 + (wg >> 3);
    const int nb   = swz % 250;
    const int mb   = swz / 250;
    const int tid  = threadIdx.x;
    const int lane = tid & 63;
    const int w    = tid >> 6;
    const int wm   = w >> 1, wn = w & 1;
    const int row0 = mb * BM, col0 = nb * BN;

    float4v acc[4][4];
#pragma unroll
    for (int i = 0; i < 4; i++)
#pragma unroll
        for (int j = 0; j < 4; j++) acc[i][j] = float4v{0.f, 0.f, 0.f, 0.f};

    for (int kt = 0; kt < HIDDEN / BK; kt++) {
#pragma unroll
        for (int i = 0; i < 4; i++) {
            int s   = i * 256 + tid;
            int row = s >> 3;
            int off = (s & 7) * 8;
            gload_lds16(A + (size_t)(row0 + row) * HIDDEN + kt * BK + off, &As[s * 8]);
            gload_lds16(B + (size_t)(col0 + row) * HIDDEN + kt * BK + off, &Bs[s * 8]);
        }
        __syncthreads();
#pragma unroll
        for (int kk = 0; kk < 2; kk++) {
            short8v af[4], bf[4];
#pragma unroll
            for (int i = 0; i < 4; i++) {
                int ar = wm * 64 + i * 16 + (lane & 15);
                af[i] = *(short8v*)&As[ar * BK + kk * 32 + (lane >> 4) * 8];
                int br = wn * 64 + i * 16 + (lane & 15);
                bf[i] = *(short8v*)&Bs[br * BK + kk * 32 + (lane >> 4) * 8];
            }
#pragma unroll
            for (int i = 0; i < 4; i++)
#pragma unroll
                for (int j = 0; j < 4; j++)
                    acc[i][j] = __builtin_amdgcn_mfma_f32_16x16x32_bf16(af[i], bf[j], acc[i][j], 0, 0, 0);
        }
        __syncthreads();
    }
#pragma unroll
    for (int i = 0; i < 4; i++) {
        int grow = row0 + wm * 64 + i * 16 + (lane >> 4) * 4;
#pragma unroll
        for (int j = 0; j < 4; j++) {
            int gcol   = col0 + wn * 64 + j * 16 + (lane & 15);
            float bias = bo[gcol];
#pragma unroll
            for (int r = 0; r < 4; r++) {
                out[(size_t)(grow + r) * VOCAB + gcol] = acc[i][j][r] + bias;
            }
        }
    }
}

// ---------------- host ----------------

extern "C" void kernel_launch(void* const* d_in, const int* in_sizes, int n_in,
                              void* d_out, int out_size, void* d_ws, size_t ws_size,
                              hipStream_t stream) {
    const int*   x     = (const int*)d_in[0];
    const float* state = (const float*)d_in[1];
    const float* W_xr  = (const float*)d_in[2];
    const float* W_hr  = (const float*)d_in[3];
    const float* b_r   = (const float*)d_in[4];
    const float* W_xz  = (const float*)d_in[5];
    const float* W_hz  = (const float*)d_in[6];
    const float* b_z   = (const float*)d_in[7];
    const float* W_xh  = (const float*)d_in[8];
    const float* W_hh  = (const float*)d_in[9];
    const float* b_h   = (const float*)d_in[10];
    const float* W_ho  = (const float*)d_in[11];
    const float* b_o   = (const float*)d_in[12];

    float* out    = (float*)d_out;
    float* hstate = out + (size_t)SEQ * BATCH * VOCAB;

    // ws layout (bytes):
    //   0        : hall  bf16 [128*32][1024]   8,388,608
    //   8388608  : bt    bf16 [32000][1024]   65,536,000
    //   73924608 : wrt   bf16 [1024][1024]     2,097,152
    //   76021760 : wzt   bf16                  2,097,152
    //   78118912 : wht   bf16                  2,097,152
    //   80216064 : hbf   bf16 [2][32][1024]      131,072
    //   80347136 : rh    bf16 [32][1024]          65,536
    //   80412672 : flags u32  [2][64]               512
    char* ws = (char*)d_ws;
    unsigned short* hall  = (unsigned short*)ws;
    unsigned short* bt    = (unsigned short*)(ws + 8388608);
    unsigned short* wrt   = (unsigned short*)(ws + 73924608);
    unsigned short* wzt   = (unsigned short*)(ws + 76021760);
    unsigned short* wht   = (unsigned short*)(ws + 78118912);
    unsigned short* hbf   = (unsigned short*)(ws + 80216064);
    unsigned short* rh    = (unsigned short*)(ws + 80347136);
    unsigned int*   flags = (unsigned int*)(ws + 80412672);

    hipMemsetAsync(flags, 0, 512, stream);
    k_transpose_bf<<<dim3(16, 16), 256, 0, stream>>>(W_hr, wrt, HIDDEN, HIDDEN);
    k_transpose_bf<<<dim3(16, 16), 256, 0, stream>>>(W_hz, wzt, HIDDEN, HIDDEN);
    k_transpose_bf<<<dim3(16, 16), 256, 0, stream>>>(W_hh, wht, HIDDEN, HIDDEN);
    k_transpose_bf<<<dim3(500, 16), 256, 0, stream>>>(W_ho, bt, VOCAB, HIDDEN);
    k_init_hbf<<<128, 256, 0, stream>>>(state, hbf);

    k_rnn<<<128, 256, 0, stream>>>(x, state, wrt, wzt, wht, W_xr, b_r, W_xz, b_z, W_xh, b_h,
                                   hbf, rh, hall, hstate, flags);

    k_gemm<<<dim3(250, 32), 256, 0, stream>>>(hall, bt, b_o, out);
}

// Round 5
// 1525.057 us; speedup vs baseline: 5.4880x; 1.1298x over previous
//
#include <hip/hip_runtime.h>
#include <hip/hip_bf16.h>
#include <cstdint>
#include <cstddef>

#define VOCAB 32000
#define HIDDEN 1024
#define BATCH 32
#define SEQ 128

typedef __attribute__((ext_vector_type(8))) short short8v;
typedef __attribute__((ext_vector_type(4))) float float4v;

__device__ __forceinline__ float bf2f(unsigned short u) {
    unsigned int x = ((unsigned int)u) << 16;
    return __uint_as_float(x);
}
__device__ __forceinline__ unsigned short f2bf(float f) {
    unsigned int x = __float_as_uint(f);
    unsigned int r = x + 0x7fffu + ((x >> 16) & 1u);  // RNE
    return (unsigned short)(r >> 16);
}

// ---------------- pre-conversion: transpose fp32 [rows][cols] -> bf16 [cols][rows] ----------------
__global__ __launch_bounds__(256) void k_transpose_bf(const float* __restrict__ in,
                                                      unsigned short* __restrict__ out,
                                                      int cols, int rows) {
    __shared__ float tile[64][65];
    const int jb = blockIdx.x;
    const int kb = blockIdx.y;
    const int t  = threadIdx.x;
    const int c  = t & 63;
    const int r0 = (t >> 6) * 16;
#pragma unroll
    for (int i = 0; i < 16; i++) {
        int r = r0 + i;
        tile[r][c] = in[(size_t)(kb * 64 + r) * cols + jb * 64 + c];
    }
    __syncthreads();
#pragma unroll
    for (int i = 0; i < 16; i++) {
        int r = r0 + i;
        out[(size_t)(jb * 64 + r) * rows + kb * 64 + c] = f2bf(tile[c][r]);
    }
}

__global__ __launch_bounds__(256) void k_init_hbf(const float* __restrict__ state,
                                                  unsigned short* __restrict__ hbf) {
    int i = blockIdx.x * 256 + threadIdx.x;
    if (i < BATCH * HIDDEN) hbf[i] = f2bf(state[i]);
}

// ---------------- persistent recurrence kernel ----------------
// 128 blocks x 256 threads (4 waves). group g = bid>>6 owns batches [g*16,+16);
// block owns j-cols [jsl*16,+16). Weights in LDS (96 KB of MFMA B-fragments).
// Cross-block data via write-through (sc0 sc1) 16B stores / cache-bypass loads.
// Sync: per-WAVE producer polling — wave w consumes k-cols [w*256,+256), produced
// by blocks [w*16,+16), so it polls only those 16 flags. Publishes are per-block
// (wave 0 only) after a wave-0-local vmcnt drain of the packed 16B WT stores.
// WAR safety: any overwrite is gated on this block's 4 waves' polls, whose
// producer sets union to ALL 64 blocks at the prior tag.

#define LD8_SC(P, F0, F1, F2, F3, F4, F5, F6, F7)                      \
    asm volatile("global_load_dwordx4 %0, %8, off sc0 sc1\n\t"         \
                 "global_load_dwordx4 %1, %8, off offset:64 sc0 sc1\n\t"  \
                 "global_load_dwordx4 %2, %8, off offset:128 sc0 sc1\n\t" \
                 "global_load_dwordx4 %3, %8, off offset:192 sc0 sc1\n\t" \
                 "global_load_dwordx4 %4, %8, off offset:256 sc0 sc1\n\t" \
                 "global_load_dwordx4 %5, %8, off offset:320 sc0 sc1\n\t" \
                 "global_load_dwordx4 %6, %8, off offset:384 sc0 sc1\n\t" \
                 "global_load_dwordx4 %7, %8, off offset:448 sc0 sc1"     \
                 : "=&v"(F0), "=&v"(F1), "=&v"(F2), "=&v"(F3),         \
                   "=&v"(F4), "=&v"(F5), "=&v"(F6), "=&v"(F7)          \
                 : "v"(P)                                              \
                 : "memory")

#define WAIT_VM0 asm volatile("s_waitcnt vmcnt(0)" ::: "memory")

#define ST16_WT(P, V) \
    asm volatile("global_store_dwordx4 %0, %1, off sc0 sc1" ::"v"(P), "v"(V) : "memory")

__device__ __forceinline__ void wave_poll(const unsigned int* flags, int prodbase,
                                          unsigned int tag) {
    const int l = threadIdx.x & 63;
    const unsigned int* p = flags + prodbase + (l & 15);
    while (true) {
        unsigned int v = __hip_atomic_load(p, __ATOMIC_RELAXED, __HIP_MEMORY_SCOPE_AGENT);
        if (__all((int)(v >= tag))) break;
        __builtin_amdgcn_s_sleep(1);
    }
}

__global__ __launch_bounds__(256, 1) void k_rnn(const int* __restrict__ x,
                                                const float* __restrict__ state,
                                                const unsigned short* __restrict__ wrt,
                                                const unsigned short* __restrict__ wzt,
                                                const unsigned short* __restrict__ wht,
                                                const float* __restrict__ W_xr, const float* __restrict__ b_r,
                                                const float* __restrict__ W_xz, const float* __restrict__ b_z,
                                                const float* __restrict__ W_xh, const float* __restrict__ b_h,
                                                unsigned short* __restrict__ hbf,   // [2][32][1024]
                                                unsigned short* __restrict__ rhbuf, // [32][1024]
                                                unsigned short* __restrict__ hall,  // [128][32][1024]
                                                float* __restrict__ hstate_out,     // [32][1024]
                                                unsigned int* __restrict__ flags) { // [2][64]
    const int bid  = blockIdx.x;
    const int g    = bid >> 6;
    const int jsl  = bid & 63;
    const int j0   = jsl * 16;
    const int b0   = g * 16;
    const int tid  = threadIdx.x;
    const int w    = tid >> 6;
    const int l    = tid & 63;
    const int llo  = l & 15;
    const int lhi  = l >> 4;
    const int bloc = tid >> 4;
    const int je   = tid & 15;
    const int bg   = b0 + bloc;
    const int jg   = j0 + je;

    unsigned int* myflag = flags + g * 64;

    __shared__ short8v wlds[3][4][8][64];  // 96 KB: [mat][wave][ks-sub][lane]
    __shared__ float red[3][4][16][17];    // 13 KB
    __shared__ short8v packA[32];          // 512 B: rh 16x16 bf16 tile
    __shared__ short8v packB[32];          // 512 B: h  16x16 bf16 tile
    __shared__ int xs[BATCH * SEQ];        // 16 KB tokens

    // ---- one-time: weights -> LDS, tokens -> LDS ----
    {
        const size_t base = (size_t)(j0 + llo) * HIDDEN + lhi * 8;
#pragma unroll
        for (int i = 0; i < 8; i++) {
            const size_t off = base + (size_t)(w * 8 + i) * 32;
            wlds[0][w][i][l] = *(const short8v*)&wrt[off];
            wlds[1][w][i][l] = *(const short8v*)&wzt[off];
            wlds[2][w][i][l] = *(const short8v*)&wht[off];
        }
        for (int i = tid; i < BATCH * SEQ; i += 256) xs[i] = x[i];
    }
    const float brv = b_r[jg], bzv = b_z[jg], bhv = b_h[jg];
    float hO = state[bg * HIDDEN + jg];
    __syncthreads();

    for (int t = 0; t < SEQ; t++) {
        const unsigned short* hcur = hbf + (t & 1) * (BATCH * HIDDEN);
        unsigned short* hnext      = hbf + ((t + 1) & 1) * (BATCH * HIDDEN);

        // embedding gathers: issued before the poll so latency hides under it
        const int tok  = xs[bg * SEQ + t];
        const float xr = W_xr[(size_t)tok * HIDDEN + jg];
        const float xz = W_xz[(size_t)tok * HIDDEN + jg];
        const float xh = W_xh[(size_t)tok * HIDDEN + jg];

        // ---- Phase A: wait for my k-slice's h producers, then r,z matmuls ----
        if (t) wave_poll(myflag, w * 16, 2u * (unsigned)t);

        short8v a0, a1, a2, a3, a4, a5, a6, a7;
        const unsigned short* pa = &hcur[(b0 + llo) * HIDDEN + w * 256 + lhi * 8];
        LD8_SC(pa, a0, a1, a2, a3, a4, a5, a6, a7);

        short8v fr[8], fz[8];
#pragma unroll
        for (int i = 0; i < 8; i++) {
            fr[i] = wlds[0][w][i][l];
            fz[i] = wlds[1][w][i][l];
        }
        WAIT_VM0;
        __builtin_amdgcn_sched_barrier(0);

        short8v af[8] = {a0, a1, a2, a3, a4, a5, a6, a7};
        float4v accR = {0.f, 0.f, 0.f, 0.f}, accZ = {0.f, 0.f, 0.f, 0.f};
#pragma unroll
        for (int i = 0; i < 8; i++) {
            accR = __builtin_amdgcn_mfma_f32_16x16x32_bf16(af[i], fr[i], accR, 0, 0, 0);
            accZ = __builtin_amdgcn_mfma_f32_16x16x32_bf16(af[i], fz[i], accZ, 0, 0, 0);
        }
#pragma unroll
        for (int q = 0; q < 4; q++) {
            red[0][w][4 * lhi + q][llo] = accR[q];
            red[1][w][4 * lhi + q][llo] = accZ[q];
        }
        __syncthreads();
        float sr = red[0][0][bloc][je] + red[0][1][bloc][je] + red[0][2][bloc][je] +
                   red[0][3][bloc][je] + xr + brv;
        float sz = red[1][0][bloc][je] + red[1][1][bloc][je] + red[1][2][bloc][je] +
                   red[1][3][bloc][je] + xz + bzv;
        float rv = 1.f / (1.f + __expf(-sr));
        float zv = 1.f / (1.f + __expf(-sz));
        ((unsigned short*)packA)[bloc * 16 + je] = f2bf(rv * hO);
        __syncthreads();
        if (w == 0) {  // packed 16B WT stores by wave 0 only; publish after local drain
            if (l < 32) {
                const int row = l >> 1, half = l & 1;
                short8v v = packA[l];
                ST16_WT(&rhbuf[(b0 + row) * HIDDEN + j0 + half * 8], v);
            }
            WAIT_VM0;
            if (l == 0)
                __hip_atomic_store(&myflag[jsl], 2u * (unsigned)t + 1u, __ATOMIC_RELAXED,
                                   __HIP_MEMORY_SCOPE_AGENT);
        }

        // ---- Phase B: wait for my k-slice's rh producers, candidate matmul ----
        wave_poll(myflag, w * 16, 2u * (unsigned)t + 1u);

        short8v c0, c1, c2, c3, c4, c5, c6, c7;
        const unsigned short* pb = &rhbuf[(b0 + llo) * HIDDEN + w * 256 + lhi * 8];
        LD8_SC(pb, c0, c1, c2, c3, c4, c5, c6, c7);

        short8v fh[8];
#pragma unroll
        for (int i = 0; i < 8; i++) fh[i] = wlds[2][w][i][l];
        WAIT_VM0;
        __builtin_amdgcn_sched_barrier(0);

        short8v ar[8] = {c0, c1, c2, c3, c4, c5, c6, c7};
        float4v accC = {0.f, 0.f, 0.f, 0.f};
#pragma unroll
        for (int i = 0; i < 8; i++)
            accC = __builtin_amdgcn_mfma_f32_16x16x32_bf16(ar[i], fh[i], accC, 0, 0, 0);
#pragma unroll
        for (int q = 0; q < 4; q++) red[2][w][4 * lhi + q][llo] = accC[q];
        __syncthreads();
        float scnd = red[2][0][bloc][je] + red[2][1][bloc][je] + red[2][2][bloc][je] +
                     red[2][3][bloc][je] + xh + bhv;
        scnd = fminf(15.f, fmaxf(-15.f, scnd));
        float e2   = __expf(2.f * scnd);
        float cand = (e2 - 1.f) / (e2 + 1.f);
        float hn   = zv * hO + (1.f - zv) * cand;
        hO = hn;
        ((unsigned short*)packB)[bloc * 16 + je] = f2bf(hn);
        __syncthreads();
        if (w == 0) {  // lanes 0-31: hnext (WT); lanes 32-63: hall (plain)
            const int l2 = l & 31, row = l2 >> 1, half = l2 & 1;
            short8v v = packB[l2];
            if (l < 32) {
                ST16_WT(&hnext[(b0 + row) * HIDDEN + j0 + half * 8], v);
            } else {
                *(short8v*)&hall[((size_t)t * BATCH + b0 + row) * HIDDEN + j0 + half * 8] = v;
            }
            WAIT_VM0;
            if (l == 0)
                __hip_atomic_store(&myflag[jsl], 2u * (unsigned)t + 2u, __ATOMIC_RELAXED,
                                   __HIP_MEMORY_SCOPE_AGENT);
        }
    }

    hstate_out[bg * HIDDEN + jg] = hO;
}

// ---------------- output-projection GEMM ----------------
#define BM 128
#define BN 128
#define BK 64

__device__ __forceinline__ void gload_lds16(const void* g, void* l) {
    __builtin_amdgcn_global_load_lds((const __attribute__((address_space(1))) void*)g,
                                     (__attribute__((address_space(3))) void*)l, 16, 0, 0);
}

__global__ __launch_bounds__(256, 2) void k_gemm(const unsigned short* __restrict__ A,
                                                 const unsigned short* __restrict__ B,
                                                 const float* __restrict__ bo,
                                                 float* __restrict__ out) {
    __shared__ unsigned short As[BM * BK];
    __shared__ unsigned short Bs[BN * BK];
    const int wg   = blockIdx.y * 250 + blockIdx.x;
    const int swz  = (wg & 7) * 1000 + (wg >> 3);
    const int nb   = swz % 250;
    const int mb   = swz / 250;
    const int tid  = threadIdx.x;
    const int lane = tid & 63;
    const int w    = tid >> 6;
    const int wm   = w >> 1, wn = w & 1;
    const int row0 = mb * BM, col0 = nb * BN;

    float4v acc[4][4];
#pragma unroll
    for (int i = 0; i < 4; i++)
#pragma unroll
        for (int j = 0; j < 4; j++) acc[i][j] = float4v{0.f, 0.f, 0.f, 0.f};

    for (int kt = 0; kt < HIDDEN / BK; kt++) {
#pragma unroll
        for (int i = 0; i < 4; i++) {
            int s   = i * 256 + tid;
            int row = s >> 3;
            int off = (s & 7) * 8;
            gload_lds16(A + (size_t)(row0 + row) * HIDDEN + kt * BK + off, &As[s * 8]);
            gload_lds16(B + (size_t)(col0 + row) * HIDDEN + kt * BK + off, &Bs[s * 8]);
        }
        __syncthreads();
#pragma unroll
        for (int kk = 0; kk < 2; kk++) {
            short8v af[4], bf[4];
#pragma unroll
            for (int i = 0; i < 4; i++) {
                int ar = wm * 64 + i * 16 + (lane & 15);
                af[i] = *(short8v*)&As[ar * BK + kk * 32 + (lane >> 4) * 8];
                int br = wn * 64 + i * 16 + (lane & 15);
                bf[i] = *(short8v*)&Bs[br * BK + kk * 32 + (lane >> 4) * 8];
            }
#pragma unroll
            for (int i = 0; i < 4; i++)
#pragma unroll
                for (int j = 0; j < 4; j++)
                    acc[i][j] = __builtin_amdgcn_mfma_f32_16x16x32_bf16(af[i], bf[j], acc[i][j], 0, 0, 0);
        }
        __syncthreads();
    }
#pragma unroll
    for (int i = 0; i < 4; i++) {
        int grow = row0 + wm * 64 + i * 16 + (lane >> 4) * 4;
#pragma unroll
        for (int j = 0; j < 4; j++) {
            int gcol   = col0 + wn * 64 + j * 16 + (lane & 15);
            float bias = bo[gcol];
#pragma unroll
            for (int r = 0; r < 4; r++) {
                out[(size_t)(grow + r) * VOCAB + gcol] = acc[i][j][r] + bias;
            }
        }
    }
}

// ---------------- host ----------------

extern "C" void kernel_launch(void* const* d_in, const int* in_sizes, int n_in,
                              void* d_out, int out_size, void* d_ws, size_t ws_size,
                              hipStream_t stream) {
    const int*   x     = (const int*)d_in[0];
    const float* state = (const float*)d_in[1];
    const float* W_xr  = (const float*)d_in[2];
    const float* W_hr  = (const float*)d_in[3];
    const float* b_r   = (const float*)d_in[4];
    const float* W_xz  = (const float*)d_in[5];
    const float* W_hz  = (const float*)d_in[6];
    const float* b_z   = (const float*)d_in[7];
    const float* W_xh  = (const float*)d_in[8];
    const float* W_hh  = (const float*)d_in[9];
    const float* b_h   = (const float*)d_in[10];
    const float* W_ho  = (const float*)d_in[11];
    const float* b_o   = (const float*)d_in[12];

    float* out    = (float*)d_out;
    float* hstate = out + (size_t)SEQ * BATCH * VOCAB;

    // ws layout (bytes):
    //   0        : hall  bf16 [128*32][1024]   8,388,608
    //   8388608  : bt    bf16 [32000][1024]   65,536,000
    //   73924608 : wrt   bf16 [1024][1024]     2,097,152
    //   76021760 : wzt   bf16                  2,097,152
    //   78118912 : wht   bf16                  2,097,152
    //   80216064 : hbf   bf16 [2][32][1024]      131,072
    //   80347136 : rh    bf16 [32][1024]          65,536
    //   80412672 : flags u32  [2][64]               512
    char* ws = (char*)d_ws;
    unsigned short* hall  = (unsigned short*)ws;
    unsigned short* bt    = (unsigned short*)(ws + 8388608);
    unsigned short* wrt   = (unsigned short*)(ws + 73924608);
    unsigned short* wzt   = (unsigned short*)(ws + 76021760);
    unsigned short* wht   = (unsigned short*)(ws + 78118912);
    unsigned short* hbf   = (unsigned short*)(ws + 80216064);
    unsigned short* rh    = (unsigned short*)(ws + 80347136);
    unsigned int*   flags = (unsigned int*)(ws + 80412672);

    hipMemsetAsync(flags, 0, 512, stream);
    k_transpose_bf<<<dim3(16, 16), 256, 0, stream>>>(W_hr, wrt, HIDDEN, HIDDEN);
    k_transpose_bf<<<dim3(16, 16), 256, 0, stream>>>(W_hz, wzt, HIDDEN, HIDDEN);
    k_transpose_bf<<<dim3(16, 16), 256, 0, stream>>>(W_hh, wht, HIDDEN, HIDDEN);
    k_transpose_bf<<<dim3(500, 16), 256, 0, stream>>>(W_ho, bt, VOCAB, HIDDEN);
    k_init_hbf<<<128, 256, 0, stream>>>(state, hbf);

    k_rnn<<<128, 256, 0, stream>>>(x, state, wrt, wzt, wht, W_xr, b_r, W_xz, b_z, W_xh, b_h,
                                   hbf, rh, hall, hstate, flags);

    k_gemm<<<dim3(250, 32), 256, 0, stream>>>(hall, bt, b_o, out);
}

// Round 6
// 1445.420 us; speedup vs baseline: 5.7904x; 1.0551x over previous
//
#include <hip/hip_runtime.h>
#include <hip/hip_bf16.h>
#include <cstdint>
#include <cstddef>

#define VOCAB 32000
#define HIDDEN 1024
#define BATCH 32
#define SEQ 128

typedef __attribute__((ext_vector_type(8))) short short8v;
typedef __attribute__((ext_vector_type(4))) float float4v;
typedef __attribute__((ext_vector_type(2))) unsigned int uint2v;

__device__ __forceinline__ float bf2f(unsigned short u) {
    unsigned int x = ((unsigned int)u) << 16;
    return __uint_as_float(x);
}
__device__ __forceinline__ unsigned short f2bf(float f) {
    unsigned int x = __float_as_uint(f);
    unsigned int r = x + 0x7fffu + ((x >> 16) & 1u);  // RNE
    return (unsigned short)(r >> 16);
}

// ---------------- pre-conversion: transpose fp32 [rows][cols] -> bf16 [cols][rows] ----------------
__global__ __launch_bounds__(256) void k_transpose_bf(const float* __restrict__ in,
                                                      unsigned short* __restrict__ out,
                                                      int cols, int rows) {
    __shared__ float tile[64][65];
    const int jb = blockIdx.x;
    const int kb = blockIdx.y;
    const int t  = threadIdx.x;
    const int c  = t & 63;
    const int r0 = (t >> 6) * 16;
#pragma unroll
    for (int i = 0; i < 16; i++) {
        int r = r0 + i;
        tile[r][c] = in[(size_t)(kb * 64 + r) * cols + jb * 64 + c];
    }
    __syncthreads();
#pragma unroll
    for (int i = 0; i < 16; i++) {
        int r = r0 + i;
        out[(size_t)(jb * 64 + r) * rows + kb * 64 + c] = f2bf(tile[c][r]);
    }
}

__global__ __launch_bounds__(256) void k_init_hbf(const float* __restrict__ state,
                                                  unsigned short* __restrict__ hinit) {
    int i = blockIdx.x * 256 + threadIdx.x;
    if (i < BATCH * HIDDEN) hinit[i] = f2bf(state[i]);
}

// ---------------- persistent recurrence kernel ----------------
// 128 blocks x 64 threads (ONE wave per block -> no __syncthreads in the loop).
// group g = bid>>6 owns batches [g*16,+16); block owns j-cols [jsl*16,+16).
// Weights in LDS (96 KB of MFMA B-fragments); full K=1024 per wave via two
// interleaved accumulator chains per gate.
// Exchange buffers ROTATE per step (write-once): rh -> rhall[t], h -> hall[t]
// (hall doubles as the GEMM A matrix). Consumers use PLAIN CACHED loads --
// legal because every line's first access on a CU happens after its poll, and
// data is identical across graph replays (deterministic). Producers write
// through (sc0 sc1), drain vmcnt, then lane 0 publishes a monotone agent-scope
// flag; each wave polls the 64 flags of its group with one 64-lane load.

#define WAIT_VM0 asm volatile("s_waitcnt vmcnt(0)" ::: "memory")
#define LGKM0    asm volatile("s_waitcnt lgkmcnt(0)" ::: "memory")

#define ST8_WT(P, V) \
    asm volatile("global_store_dwordx2 %0, %1, off sc0 sc1" ::"v"(P), "v"(V) : "memory")

__device__ __forceinline__ void wave_poll64(const unsigned int* flags, unsigned int tag) {
    const unsigned int* p = flags + (threadIdx.x & 63);
    while (true) {
        unsigned int v = __hip_atomic_load(p, __ATOMIC_RELAXED, __HIP_MEMORY_SCOPE_AGENT);
        if (__all((int)(v >= tag))) break;
        __builtin_amdgcn_s_sleep(1);
    }
}

__global__ __launch_bounds__(64, 1) void k_rnn(const int* __restrict__ x,
                                               const float* __restrict__ state,
                                               const unsigned short* __restrict__ wrt,
                                               const unsigned short* __restrict__ wzt,
                                               const unsigned short* __restrict__ wht,
                                               const float* __restrict__ W_xr, const float* __restrict__ b_r,
                                               const float* __restrict__ W_xz, const float* __restrict__ b_z,
                                               const float* __restrict__ W_xh, const float* __restrict__ b_h,
                                               const unsigned short* __restrict__ hinit, // [32][1024]
                                               unsigned short* __restrict__ hall,        // [128][32][1024]
                                               unsigned short* __restrict__ rhall,       // [128][32][1024]
                                               float* __restrict__ hstate_out,           // [32][1024]
                                               unsigned int* __restrict__ flags) {       // [2][64]
    const int bid = blockIdx.x;
    const int g   = bid >> 6;
    const int jsl = bid & 63;
    const int j0  = jsl * 16;
    const int b0  = g * 16;
    const int l   = threadIdx.x;  // 0..63
    const int llo = l & 15;
    const int lhi = l >> 4;
    const int jg  = j0 + llo;

    unsigned int* myflag = flags + g * 64;

    __shared__ short8v wlds[3][32][64];     // 96 KB: [mat][k-subtile][lane]
    __shared__ int xs[16 * SEQ];            // 8 KB: own group's tokens [bloc][t]
    __shared__ unsigned short pack[16 * 16];// 512 B exchange tile

    // ---- one-time: weights -> LDS (B-frags), tokens -> LDS ----
#pragma unroll
    for (int i = 0; i < 32; i++) {
        const size_t off = (size_t)jg * HIDDEN + i * 32 + lhi * 8;
        wlds[0][i][l] = *(const short8v*)&wrt[off];
        wlds[1][i][l] = *(const short8v*)&wzt[off];
        wlds[2][i][l] = *(const short8v*)&wht[off];
    }
    for (int i = l; i < 16 * SEQ; i += 64)
        xs[i] = x[(size_t)(b0 + (i >> 7)) * SEQ + (i & 127)];

    const float brv = b_r[jg], bzv = b_z[jg], bhv = b_h[jg];
    float4v hO;
#pragma unroll
    for (int q = 0; q < 4; q++) hO[q] = state[(b0 + 4 * lhi + q) * HIDDEN + jg];
    LGKM0;  // LDS preload visible to own wave's reads

    for (int t = 0; t < SEQ; t++) {
        const unsigned short* hprev =
            t ? (hall + (size_t)(t - 1) * BATCH * HIDDEN) : hinit;
        unsigned short* rhp = rhall + (size_t)t * BATCH * HIDDEN;
        unsigned short* hp  = hall + (size_t)t * BATCH * HIDDEN;

        // embedding gathers issued BEFORE the poll (latency hides under it)
        int tok[4];
#pragma unroll
        for (int q = 0; q < 4; q++) tok[q] = xs[(4 * lhi + q) * SEQ + t];
        float xr[4], xz[4], xh[4];
#pragma unroll
        for (int q = 0; q < 4; q++) {
            xr[q] = W_xr[(size_t)tok[q] * HIDDEN + jg];
            xz[q] = W_xz[(size_t)tok[q] * HIDDEN + jg];
            xh[q] = W_xh[(size_t)tok[q] * HIDDEN + jg];
        }

        // ---- Phase A: wait h(t-1), compute r,z ----
        if (t) wave_poll64(myflag, 2u * (unsigned)t);

        short8v af[32];
#pragma unroll
        for (int i = 0; i < 32; i++)
            af[i] = *(const short8v*)&hprev[(b0 + llo) * HIDDEN + i * 32 + lhi * 8];

        float4v aR0 = {0.f, 0.f, 0.f, 0.f}, aR1 = {0.f, 0.f, 0.f, 0.f};
        float4v aZ0 = {0.f, 0.f, 0.f, 0.f}, aZ1 = {0.f, 0.f, 0.f, 0.f};
#pragma unroll
        for (int i = 0; i < 32; i += 2) {
            aR0 = __builtin_amdgcn_mfma_f32_16x16x32_bf16(af[i],     wlds[0][i][l],     aR0, 0, 0, 0);
            aZ0 = __builtin_amdgcn_mfma_f32_16x16x32_bf16(af[i],     wlds[1][i][l],     aZ0, 0, 0, 0);
            aR1 = __builtin_amdgcn_mfma_f32_16x16x32_bf16(af[i + 1], wlds[0][i + 1][l], aR1, 0, 0, 0);
            aZ1 = __builtin_amdgcn_mfma_f32_16x16x32_bf16(af[i + 1], wlds[1][i + 1][l], aZ1, 0, 0, 0);
        }

        float4v zv;
#pragma unroll
        for (int q = 0; q < 4; q++) {
            float sr = aR0[q] + aR1[q] + xr[q] + brv;
            float sz = aZ0[q] + aZ1[q] + xz[q] + bzv;
            float rv = 1.f / (1.f + __expf(-sr));
            zv[q]    = 1.f / (1.f + __expf(-sz));
            pack[(4 * lhi + q) * 16 + llo] = f2bf(rv * hO[q]);
        }
        LGKM0;
        __builtin_amdgcn_wave_barrier();
        {   // publish rh tile: 64 lanes x 8B write-through, drain, flag
            uint2v v = *(const uint2v*)&pack[(l >> 2) * 16 + (l & 3) * 4];
            ST8_WT(&rhp[(b0 + (l >> 2)) * HIDDEN + j0 + (l & 3) * 4], v);
            WAIT_VM0;
            if (l == 0)
                __hip_atomic_store(&myflag[jsl], 2u * (unsigned)t + 1u, __ATOMIC_RELAXED,
                                   __HIP_MEMORY_SCOPE_AGENT);
        }

        // ---- Phase B: wait rh, compute candidate + update ----
        wave_poll64(myflag, 2u * (unsigned)t + 1u);

        short8v ar[32];
#pragma unroll
        for (int i = 0; i < 32; i++)
            ar[i] = *(const short8v*)&rhp[(b0 + llo) * HIDDEN + i * 32 + lhi * 8];

        float4v aC0 = {0.f, 0.f, 0.f, 0.f}, aC1 = {0.f, 0.f, 0.f, 0.f};
#pragma unroll
        for (int i = 0; i < 32; i += 2) {
            aC0 = __builtin_amdgcn_mfma_f32_16x16x32_bf16(ar[i],     wlds[2][i][l],     aC0, 0, 0, 0);
            aC1 = __builtin_amdgcn_mfma_f32_16x16x32_bf16(ar[i + 1], wlds[2][i + 1][l], aC1, 0, 0, 0);
        }
#pragma unroll
        for (int q = 0; q < 4; q++) {
            float a = aC0[q] + aC1[q] + xh[q] + bhv;
            a = fminf(15.f, fmaxf(-15.f, a));
            float e2   = __expf(2.f * a);
            float cand = (e2 - 1.f) / (e2 + 1.f);
            float hn   = zv[q] * hO[q] + (1.f - zv[q]) * cand;
            hO[q]      = hn;
            pack[(4 * lhi + q) * 16 + llo] = f2bf(hn);
        }
        LGKM0;
        __builtin_amdgcn_wave_barrier();
        {   // publish h tile into hall[t] (doubles as GEMM A matrix)
            uint2v v = *(const uint2v*)&pack[(l >> 2) * 16 + (l & 3) * 4];
            ST8_WT(&hp[(b0 + (l >> 2)) * HIDDEN + j0 + (l & 3) * 4], v);
            WAIT_VM0;
            if (l == 0)
                __hip_atomic_store(&myflag[jsl], 2u * (unsigned)t + 2u, __ATOMIC_RELAXED,
                                   __HIP_MEMORY_SCOPE_AGENT);
        }
    }

#pragma unroll
    for (int q = 0; q < 4; q++)
        hstate_out[(b0 + 4 * lhi + q) * HIDDEN + jg] = hO[q];
}

// ---------------- output-projection GEMM ----------------
#define BM 128
#define BN 128
#define BK 64

__device__ __forceinline__ void gload_lds16(const void* g, void* l) {
    __builtin_amdgcn_global_load_lds((const __attribute__((address_space(1))) void*)g,
                                     (__attribute__((address_space(3))) void*)l, 16, 0, 0);
}

__global__ __launch_bounds__(256, 2) void k_gemm(const unsigned short* __restrict__ A,
                                                 const unsigned short* __restrict__ B,
                                                 const float* __restrict__ bo,
                                                 float* __restrict__ out) {
    __shared__ unsigned short As[BM * BK];
    __shared__ unsigned short Bs[BN * BK];
    const int wg   = blockIdx.y * 250 + blockIdx.x;
    const int swz  = (wg & 7) * 1000 + (wg >> 3);
    const int nb   = swz % 250;
    const int mb   = swz / 250;
    const int tid  = threadIdx.x;
    const int lane = tid & 63;
    const int w    = tid >> 6;
    const int wm   = w >> 1, wn = w & 1;
    const int row0 = mb * BM, col0 = nb * BN;

    float4v acc[4][4];
#pragma unroll
    for (int i = 0; i < 4; i++)
#pragma unroll
        for (int j = 0; j < 4; j++) acc[i][j] = float4v{0.f, 0.f, 0.f, 0.f};

    for (int kt = 0; kt < HIDDEN / BK; kt++) {
#pragma unroll
        for (int i = 0; i < 4; i++) {
            int s   = i * 256 + tid;
            int row = s >> 3;
            int off = (s & 7) * 8;
            gload_lds16(A + (size_t)(row0 + row) * HIDDEN + kt * BK + off, &As[s * 8]);
            gload_lds16(B + (size_t)(col0 + row) * HIDDEN + kt * BK + off, &Bs[s * 8]);
        }
        __syncthreads();
#pragma unroll
        for (int kk = 0; kk < 2; kk++) {
            short8v af[4], bf[4];
#pragma unroll
            for (int i = 0; i < 4; i++) {
                int ar = wm * 64 + i * 16 + (lane & 15);
                af[i] = *(short8v*)&As[ar * BK + kk * 32 + (lane >> 4) * 8];
                int br = wn * 64 + i * 16 + (lane & 15);
                bf[i] = *(short8v*)&Bs[br * BK + kk * 32 + (lane >> 4) * 8];
            }
#pragma unroll
            for (int i = 0; i < 4; i++)
#pragma unroll
                for (int j = 0; j < 4; j++)
                    acc[i][j] = __builtin_amdgcn_mfma_f32_16x16x32_bf16(af[i], bf[j], acc[i][j], 0, 0, 0);
        }
        __syncthreads();
    }
#pragma unroll
    for (int i = 0; i < 4; i++) {
        int grow = row0 + wm * 64 + i * 16 + (lane >> 4) * 4;
#pragma unroll
        for (int j = 0; j < 4; j++) {
            int gcol   = col0 + wn * 64 + j * 16 + (lane & 15);
            float bias = bo[gcol];
#pragma unroll
            for (int r = 0; r < 4; r++) {
                out[(size_t)(grow + r) * VOCAB + gcol] = acc[i][j][r] + bias;
            }
        }
    }
}

// ---------------- host ----------------

extern "C" void kernel_launch(void* const* d_in, const int* in_sizes, int n_in,
                              void* d_out, int out_size, void* d_ws, size_t ws_size,
                              hipStream_t stream) {
    const int*   x     = (const int*)d_in[0];
    const float* state = (const float*)d_in[1];
    const float* W_xr  = (const float*)d_in[2];
    const float* W_hr  = (const float*)d_in[3];
    const float* b_r   = (const float*)d_in[4];
    const float* W_xz  = (const float*)d_in[5];
    const float* W_hz  = (const float*)d_in[6];
    const float* b_z   = (const float*)d_in[7];
    const float* W_xh  = (const float*)d_in[8];
    const float* W_hh  = (const float*)d_in[9];
    const float* b_h   = (const float*)d_in[10];
    const float* W_ho  = (const float*)d_in[11];
    const float* b_o   = (const float*)d_in[12];

    float* out    = (float*)d_out;
    float* hstate = out + (size_t)SEQ * BATCH * VOCAB;

    // ws layout (bytes):
    //   0        : hall  bf16 [128][32][1024]   8,388,608  (= GEMM A matrix)
    //   8388608  : rhall bf16 [128][32][1024]   8,388,608
    //   16777216 : bt    bf16 [32000][1024]    65,536,000
    //   82313216 : wrt   bf16 [1024][1024]      2,097,152
    //   84410368 : wzt   bf16                   2,097,152
    //   86507520 : wht   bf16                   2,097,152
    //   88604672 : hinit bf16 [32][1024]           65,536
    //   88670208 : flags u32  [2][64]                 512    total ~88.7 MB
    char* ws = (char*)d_ws;
    unsigned short* hall  = (unsigned short*)ws;
    unsigned short* rhall = (unsigned short*)(ws + 8388608);
    unsigned short* bt    = (unsigned short*)(ws + 16777216);
    unsigned short* wrt   = (unsigned short*)(ws + 82313216);
    unsigned short* wzt   = (unsigned short*)(ws + 84410368);
    unsigned short* wht   = (unsigned short*)(ws + 86507520);
    unsigned short* hinit = (unsigned short*)(ws + 88604672);
    unsigned int*   flags = (unsigned int*)(ws + 88670208);

    hipMemsetAsync(flags, 0, 512, stream);
    k_transpose_bf<<<dim3(16, 16), 256, 0, stream>>>(W_hr, wrt, HIDDEN, HIDDEN);
    k_transpose_bf<<<dim3(16, 16), 256, 0, stream>>>(W_hz, wzt, HIDDEN, HIDDEN);
    k_transpose_bf<<<dim3(16, 16), 256, 0, stream>>>(W_hh, wht, HIDDEN, HIDDEN);
    k_transpose_bf<<<dim3(500, 16), 256, 0, stream>>>(W_ho, bt, VOCAB, HIDDEN);
    k_init_hbf<<<128, 256, 0, stream>>>(state, hinit);

    k_rnn<<<128, 64, 0, stream>>>(x, state, wrt, wzt, wht, W_xr, b_r, W_xz, b_z, W_xh, b_h,
                                  hinit, hall, rhall, hstate, flags);

    k_gemm<<<dim3(250, 32), 256, 0, stream>>>(hall, bt, b_o, out);
}

// Round 7
// 1289.922 us; speedup vs baseline: 6.4884x; 1.1205x over previous
//
#include <hip/hip_runtime.h>
#include <hip/hip_bf16.h>
#include <cstdint>
#include <cstddef>

#define VOCAB 32000
#define HIDDEN 1024
#define BATCH 32
#define SEQ 128

typedef __attribute__((ext_vector_type(8))) short short8v;
typedef __attribute__((ext_vector_type(4))) float float4v;
typedef __attribute__((ext_vector_type(2))) unsigned int uint2v;

__device__ __forceinline__ float bf2f(unsigned short u) {
    unsigned int x = ((unsigned int)u) << 16;
    return __uint_as_float(x);
}
__device__ __forceinline__ unsigned short f2bf(float f) {
    unsigned int x = __float_as_uint(f);
    unsigned int r = x + 0x7fffu + ((x >> 16) & 1u);  // RNE
    return (unsigned short)(r >> 16);
}

// ---------------- pre-conversion: transpose fp32 [rows][cols] -> bf16 [cols][rows] ----------------
__global__ __launch_bounds__(256) void k_transpose_bf(const float* __restrict__ in,
                                                      unsigned short* __restrict__ out,
                                                      int cols, int rows) {
    __shared__ float tile[64][65];
    const int jb = blockIdx.x;
    const int kb = blockIdx.y;
    const int t  = threadIdx.x;
    const int c  = t & 63;
    const int r0 = (t >> 6) * 16;
#pragma unroll
    for (int i = 0; i < 16; i++) {
        int r = r0 + i;
        tile[r][c] = in[(size_t)(kb * 64 + r) * cols + jb * 64 + c];
    }
    __syncthreads();
#pragma unroll
    for (int i = 0; i < 16; i++) {
        int r = r0 + i;
        out[(size_t)(jb * 64 + r) * rows + kb * 64 + c] = f2bf(tile[c][r]);
    }
}

__global__ __launch_bounds__(256) void k_init_hbf(const float* __restrict__ state,
                                                  unsigned short* __restrict__ hinit) {
    int i = blockIdx.x * 256 + threadIdx.x;
    if (i < BATCH * HIDDEN) hinit[i] = f2bf(state[i]);
}

// ---------------- persistent recurrence kernel ----------------
// 130 blocks x 64 threads. Blocks 0..127: workers (1 wave each); blocks 128/129:
// per-group AGGREGATOR waves. group g = bid>>6 owns batches [g*16,+16); worker
// owns j-cols [jsl*16,+16). Weights in LDS (96 KB of MFMA B-fragments).
// Exchange buffers ROTATE per step (write-once): rh -> rhall[t], h -> hall[t]
// (hall doubles as the GEMM A matrix); consumers use plain cached loads (first
// touch of any line is after its poll). Producers write through (sc0 sc1),
// drain vmcnt, lane 0 publishes a monotone per-block flag.
// NOTIFICATION TREE (kills same-line poll contention): the aggregator is the
// ONLY poller of the 64 flag dwords; it forwards each tag to 64 PRIVATE
// per-consumer mailboxes (128B apart -> distinct lines, 1 writer + 1 poller
// per line). Workers tight-poll only their own mailbox dword.

#define WAIT_VM0 asm volatile("s_waitcnt vmcnt(0)" ::: "memory")
#define LGKM0    asm volatile("s_waitcnt lgkmcnt(0)" ::: "memory")

#define ST8_WT(P, V) \
    asm volatile("global_store_dwordx2 %0, %1, off sc0 sc1" ::"v"(P), "v"(V) : "memory")

__device__ __forceinline__ void mbox_poll(const unsigned int* m, unsigned int tag) {
    while (__hip_atomic_load(m, __ATOMIC_RELAXED, __HIP_MEMORY_SCOPE_AGENT) < tag) {
    }
}

__global__ __launch_bounds__(64, 1) void k_rnn(const int* __restrict__ x,
                                               const float* __restrict__ state,
                                               const unsigned short* __restrict__ wrt,
                                               const unsigned short* __restrict__ wzt,
                                               const unsigned short* __restrict__ wht,
                                               const float* __restrict__ W_xr, const float* __restrict__ b_r,
                                               const float* __restrict__ W_xz, const float* __restrict__ b_z,
                                               const float* __restrict__ W_xh, const float* __restrict__ b_h,
                                               const unsigned short* __restrict__ hinit, // [32][1024]
                                               unsigned short* __restrict__ hall,        // [128][32][1024]
                                               unsigned short* __restrict__ rhall,       // [128][32][1024]
                                               float* __restrict__ hstate_out,           // [32][1024]
                                               unsigned int* __restrict__ flags,         // [2][64]
                                               unsigned int* __restrict__ mbox) {        // [2][64][32]
    const int bid = blockIdx.x;
    const int l   = threadIdx.x;  // 0..63

    // ---------- aggregator blocks ----------
    if (bid >= 128) {
        const int ga = bid - 128;
        unsigned int* gflags = flags + ga * 64;
        unsigned int* gmbox  = mbox + ga * 64 * 32;
        for (unsigned int p = 1; p <= 2u * SEQ; p++) {
            while (true) {
                unsigned int v = __hip_atomic_load(&gflags[l], __ATOMIC_RELAXED,
                                                   __HIP_MEMORY_SCOPE_AGENT);
                if (__all((int)(v >= p))) break;
            }
            __hip_atomic_store(&gmbox[l * 32], p, __ATOMIC_RELAXED, __HIP_MEMORY_SCOPE_AGENT);
        }
        return;
    }

    // ---------- worker blocks ----------
    const int g   = bid >> 6;
    const int jsl = bid & 63;
    const int j0  = jsl * 16;
    const int b0  = g * 16;
    const int llo = l & 15;
    const int lhi = l >> 4;
    const int jg  = j0 + llo;

    unsigned int* myflag = flags + g * 64;
    const unsigned int* mymbox = mbox + (g * 64 + jsl) * 32;

    __shared__ short8v wlds[3][32][64];     // 96 KB: [mat][k-subtile][lane]
    __shared__ int xs[16 * SEQ];            // 8 KB: own group's tokens [bloc][t]
    __shared__ unsigned short pack[16 * 16];// 512 B exchange tile

    // ---- one-time: weights -> LDS (B-frags), tokens -> LDS ----
#pragma unroll
    for (int i = 0; i < 32; i++) {
        const size_t off = (size_t)jg * HIDDEN + i * 32 + lhi * 8;
        wlds[0][i][l] = *(const short8v*)&wrt[off];
        wlds[1][i][l] = *(const short8v*)&wzt[off];
        wlds[2][i][l] = *(const short8v*)&wht[off];
    }
    for (int i = l; i < 16 * SEQ; i += 64)
        xs[i] = x[(size_t)(b0 + (i >> 7)) * SEQ + (i & 127)];

    const float brv = b_r[jg], bzv = b_z[jg], bhv = b_h[jg];
    float4v hO;
#pragma unroll
    for (int q = 0; q < 4; q++) hO[q] = state[(b0 + 4 * lhi + q) * HIDDEN + jg];
    LGKM0;  // LDS preload visible to own wave's reads

    for (int t = 0; t < SEQ; t++) {
        const unsigned short* hprev =
            t ? (hall + (size_t)(t - 1) * BATCH * HIDDEN) : hinit;
        unsigned short* rhp = rhall + (size_t)t * BATCH * HIDDEN;
        unsigned short* hp  = hall + (size_t)t * BATCH * HIDDEN;

        // embedding gathers issued BEFORE the poll (latency hides under it)
        int tok[4];
#pragma unroll
        for (int q = 0; q < 4; q++) tok[q] = xs[(4 * lhi + q) * SEQ + t];
        float xr[4], xz[4], xh[4];
#pragma unroll
        for (int q = 0; q < 4; q++) {
            xr[q] = W_xr[(size_t)tok[q] * HIDDEN + jg];
            xz[q] = W_xz[(size_t)tok[q] * HIDDEN + jg];
            xh[q] = W_xh[(size_t)tok[q] * HIDDEN + jg];
        }

        // ---- Phase A: wait h(t-1) via private mailbox, compute r,z ----
        if (t) mbox_poll(mymbox, 2u * (unsigned)t);

        short8v af[32];
#pragma unroll
        for (int i = 0; i < 32; i++)
            af[i] = *(const short8v*)&hprev[(b0 + llo) * HIDDEN + i * 32 + lhi * 8];

        float4v aR0 = {0.f, 0.f, 0.f, 0.f}, aR1 = {0.f, 0.f, 0.f, 0.f};
        float4v aZ0 = {0.f, 0.f, 0.f, 0.f}, aZ1 = {0.f, 0.f, 0.f, 0.f};
#pragma unroll
        for (int i = 0; i < 32; i += 2) {
            aR0 = __builtin_amdgcn_mfma_f32_16x16x32_bf16(af[i],     wlds[0][i][l],     aR0, 0, 0, 0);
            aZ0 = __builtin_amdgcn_mfma_f32_16x16x32_bf16(af[i],     wlds[1][i][l],     aZ0, 0, 0, 0);
            aR1 = __builtin_amdgcn_mfma_f32_16x16x32_bf16(af[i + 1], wlds[0][i + 1][l], aR1, 0, 0, 0);
            aZ1 = __builtin_amdgcn_mfma_f32_16x16x32_bf16(af[i + 1], wlds[1][i + 1][l], aZ1, 0, 0, 0);
        }

        float4v zv;
#pragma unroll
        for (int q = 0; q < 4; q++) {
            float sr = aR0[q] + aR1[q] + xr[q] + brv;
            float sz = aZ0[q] + aZ1[q] + xz[q] + bzv;
            float rv = 1.f / (1.f + __expf(-sr));
            zv[q]    = 1.f / (1.f + __expf(-sz));
            pack[(4 * lhi + q) * 16 + llo] = f2bf(rv * hO[q]);
        }
        LGKM0;
        __builtin_amdgcn_wave_barrier();
        {   // publish rh tile: 64 lanes x 8B write-through, drain, flag
            uint2v v = *(const uint2v*)&pack[(l >> 2) * 16 + (l & 3) * 4];
            ST8_WT(&rhp[(b0 + (l >> 2)) * HIDDEN + j0 + (l & 3) * 4], v);
            WAIT_VM0;
            if (l == 0)
                __hip_atomic_store(&myflag[jsl], 2u * (unsigned)t + 1u, __ATOMIC_RELAXED,
                                   __HIP_MEMORY_SCOPE_AGENT);
        }

        // ---- Phase B: wait rh via private mailbox, compute candidate + update ----
        mbox_poll(mymbox, 2u * (unsigned)t + 1u);

        short8v ar[32];
#pragma unroll
        for (int i = 0; i < 32; i++)
            ar[i] = *(const short8v*)&rhp[(b0 + llo) * HIDDEN + i * 32 + lhi * 8];

        float4v aC0 = {0.f, 0.f, 0.f, 0.f}, aC1 = {0.f, 0.f, 0.f, 0.f};
#pragma unroll
        for (int i = 0; i < 32; i += 2) {
            aC0 = __builtin_amdgcn_mfma_f32_16x16x32_bf16(ar[i],     wlds[2][i][l],     aC0, 0, 0, 0);
            aC1 = __builtin_amdgcn_mfma_f32_16x16x32_bf16(ar[i + 1], wlds[2][i + 1][l], aC1, 0, 0, 0);
        }
#pragma unroll
        for (int q = 0; q < 4; q++) {
            float a = aC0[q] + aC1[q] + xh[q] + bhv;
            a = fminf(15.f, fmaxf(-15.f, a));
            float e2   = __expf(2.f * a);
            float cand = (e2 - 1.f) / (e2 + 1.f);
            float hn   = zv[q] * hO[q] + (1.f - zv[q]) * cand;
            hO[q]      = hn;
            pack[(4 * lhi + q) * 16 + llo] = f2bf(hn);
        }
        LGKM0;
        __builtin_amdgcn_wave_barrier();
        {   // publish h tile into hall[t] (doubles as GEMM A matrix)
            uint2v v = *(const uint2v*)&pack[(l >> 2) * 16 + (l & 3) * 4];
            ST8_WT(&hp[(b0 + (l >> 2)) * HIDDEN + j0 + (l & 3) * 4], v);
            WAIT_VM0;
            if (l == 0)
                __hip_atomic_store(&myflag[jsl], 2u * (unsigned)t + 2u, __ATOMIC_RELAXED,
                                   __HIP_MEMORY_SCOPE_AGENT);
        }
    }

#pragma unroll
    for (int q = 0; q < 4; q++)
        hstate_out[(b0 + 4 * lhi + q) * HIDDEN + jg] = hO[q];
}

// ---------------- output-projection GEMM ----------------
#define BM 128
#define BN 128
#define BK 64

__device__ __forceinline__ void gload_lds16(const void* g, void* l) {
    __builtin_amdgcn_global_load_lds((const __attribute__((address_space(1))) void*)g,
                                     (__attribute__((address_space(3))) void*)l, 16, 0, 0);
}

__global__ __launch_bounds__(256, 2) void k_gemm(const unsigned short* __restrict__ A,
                                                 const unsigned short* __restrict__ B,
                                                 const float* __restrict__ bo,
                                                 float* __restrict__ out) {
    __shared__ unsigned short As[BM * BK];
    __shared__ unsigned short Bs[BN * BK];
    const int wg   = blockIdx.y * 250 + blockIdx.x;
    const int swz  = (wg & 7) * 1000 + (wg >> 3);
    const int nb   = swz % 250;
    const int mb   = swz / 250;
    const int tid  = threadIdx.x;
    const int lane = tid & 63;
    const int w    = tid >> 6;
    const int wm   = w >> 1, wn = w & 1;
    const int row0 = mb * BM, col0 = nb * BN;

    float4v acc[4][4];
#pragma unroll
    for (int i = 0; i < 4; i++)
#pragma unroll
        for (int j = 0; j < 4; j++) acc[i][j] = float4v{0.f, 0.f, 0.f, 0.f};

    for (int kt = 0; kt < HIDDEN / BK; kt++) {
#pragma unroll
        for (int i = 0; i < 4; i++) {
            int s   = i * 256 + tid;
            int row = s >> 3;
            int off = (s & 7) * 8;
            gload_lds16(A + (size_t)(row0 + row) * HIDDEN + kt * BK + off, &As[s * 8]);
            gload_lds16(B + (size_t)(col0 + row) * HIDDEN + kt * BK + off, &Bs[s * 8]);
        }
        __syncthreads();
#pragma unroll
        for (int kk = 0; kk < 2; kk++) {
            short8v af[4], bf[4];
#pragma unroll
            for (int i = 0; i < 4; i++) {
                int ar = wm * 64 + i * 16 + (lane & 15);
                af[i] = *(short8v*)&As[ar * BK + kk * 32 + (lane >> 4) * 8];
                int br = wn * 64 + i * 16 + (lane & 15);
                bf[i] = *(short8v*)&Bs[br * BK + kk * 32 + (lane >> 4) * 8];
            }
#pragma unroll
            for (int i = 0; i < 4; i++)
#pragma unroll
                for (int j = 0; j < 4; j++)
                    acc[i][j] = __builtin_amdgcn_mfma_f32_16x16x32_bf16(af[i], bf[j], acc[i][j], 0, 0, 0);
        }
        __syncthreads();
    }
#pragma unroll
    for (int i = 0; i < 4; i++) {
        int grow = row0 + wm * 64 + i * 16 + (lane >> 4) * 4;
#pragma unroll
        for (int j = 0; j < 4; j++) {
            int gcol   = col0 + wn * 64 + j * 16 + (lane & 15);
            float bias = bo[gcol];
#pragma unroll
            for (int r = 0; r < 4; r++) {
                out[(size_t)(grow + r) * VOCAB + gcol] = acc[i][j][r] + bias;
            }
        }
    }
}

// ---------------- host ----------------

extern "C" void kernel_launch(void* const* d_in, const int* in_sizes, int n_in,
                              void* d_out, int out_size, void* d_ws, size_t ws_size,
                              hipStream_t stream) {
    const int*   x     = (const int*)d_in[0];
    const float* state = (const float*)d_in[1];
    const float* W_xr  = (const float*)d_in[2];
    const float* W_hr  = (const float*)d_in[3];
    const float* b_r   = (const float*)d_in[4];
    const float* W_xz  = (const float*)d_in[5];
    const float* W_hz  = (const float*)d_in[6];
    const float* b_z   = (const float*)d_in[7];
    const float* W_xh  = (const float*)d_in[8];
    const float* W_hh  = (const float*)d_in[9];
    const float* b_h   = (const float*)d_in[10];
    const float* W_ho  = (const float*)d_in[11];
    const float* b_o   = (const float*)d_in[12];

    float* out    = (float*)d_out;
    float* hstate = out + (size_t)SEQ * BATCH * VOCAB;

    // ws layout (bytes):
    //   0        : hall  bf16 [128][32][1024]   8,388,608  (= GEMM A matrix)
    //   8388608  : rhall bf16 [128][32][1024]   8,388,608
    //   16777216 : bt    bf16 [32000][1024]    65,536,000
    //   82313216 : wrt   bf16 [1024][1024]      2,097,152
    //   84410368 : wzt   bf16                   2,097,152
    //   86507520 : wht   bf16                   2,097,152
    //   88604672 : hinit bf16 [32][1024]           65,536
    //   88670208 : flags u32  [2][64]                 512
    //   88670720 : mbox  u32  [2][64][32]          16,384   total ~88.7 MB
    char* ws = (char*)d_ws;
    unsigned short* hall  = (unsigned short*)ws;
    unsigned short* rhall = (unsigned short*)(ws + 8388608);
    unsigned short* bt    = (unsigned short*)(ws + 16777216);
    unsigned short* wrt   = (unsigned short*)(ws + 82313216);
    unsigned short* wzt   = (unsigned short*)(ws + 84410368);
    unsigned short* wht   = (unsigned short*)(ws + 86507520);
    unsigned short* hinit = (unsigned short*)(ws + 88604672);
    unsigned int*   flags = (unsigned int*)(ws + 88670208);
    unsigned int*   mbox  = (unsigned int*)(ws + 88670720);

    hipMemsetAsync(flags, 0, 512 + 16384, stream);
    k_transpose_bf<<<dim3(16, 16), 256, 0, stream>>>(W_hr, wrt, HIDDEN, HIDDEN);
    k_transpose_bf<<<dim3(16, 16), 256, 0, stream>>>(W_hz, wzt, HIDDEN, HIDDEN);
    k_transpose_bf<<<dim3(16, 16), 256, 0, stream>>>(W_hh, wht, HIDDEN, HIDDEN);
    k_transpose_bf<<<dim3(500, 16), 256, 0, stream>>>(W_ho, bt, VOCAB, HIDDEN);
    k_init_hbf<<<128, 256, 0, stream>>>(state, hinit);

    k_rnn<<<130, 64, 0, stream>>>(x, state, wrt, wzt, wht, W_xr, b_r, W_xz, b_z, W_xh, b_h,
                                  hinit, hall, rhall, hstate, flags, mbox);

    k_gemm<<<dim3(250, 32), 256, 0, stream>>>(hall, bt, b_o, out);
}